// Round 3
// baseline (341.046 us; speedup 1.0000x reference)
//
#include <hip/hip_runtime.h>
#include <hip/hip_bf16.h>

// Problem: B=4, N=2048, H=16, Dh=64, D=1024. All global tensors fp32.
// out = LN( softmax(Q K^T / 8) V @ W_out^T ) * g   (fp32 out).
// R9: attn is VALU-bound (VALUBusy 54% vs MfmaUtil 14%) on per-tile K/V
// f32 load + pack_bf2 + ds_write staging, redone 16x per (b,h). Hoist to
// one-time prep: K -> bf16 (same layout), V -> bf16 TRANSPOSED per (b,h)
// ([b][h][64][2048]), W -> bf16. attn then stages K / V^T tiles via
// global_load_lds w16 with source-side inverse XOR swizzle (LDS linear,
// read applies same XOR - rule 21). Zero staging VALU in the inner loop.
// Rounding = same pack_bf2 -> operand bits identical -> absmax unchanged.
// XCD-aware bijective block swizzles on attn (group same-(b,h) blocks per
// XCD) and proj (group same-A-panel blocks per XCD).
// Tiered ws guard: full path needs 50 MiB; falls back to R8 / R6 paths.

#define Bv 4
#define Nv 2048
#define Hv 16
#define DHv 64
#define Dv 1024
#define NT (Nv / 64)

typedef __attribute__((ext_vector_type(8))) short short8;
typedef __attribute__((ext_vector_type(4))) float floatx4;

// bf16 pair pack, round-half-up (+0x8000 then take high16 via one v_perm_b32).
__device__ inline unsigned pack_bf2(float a, float b) {
    unsigned ua = __builtin_bit_cast(unsigned, a) + 0x8000u;
    unsigned ub = __builtin_bit_cast(unsigned, b) + 0x8000u;
    return __builtin_amdgcn_perm(ub, ua, 0x07060302u);  // [b.hi16 : a.hi16]
}

// ---------------------------------------------------------------------------
// Prep: K (8M elems) and W (1M elems) f32 -> bf16, fused into one launch.
// Same pack_bf2 rounding the in-kernel staging used -> bit-identical operands.
// ---------------------------------------------------------------------------
#define KCONV_BLOCKS 4096
#define WCONV_BLOCKS 512

__global__ __launch_bounds__(256)
void prep_conv(const float* __restrict__ K, __hip_bfloat16* __restrict__ Kb,
               const float* __restrict__ W, __hip_bfloat16* __restrict__ Wb) {
    const float* src;
    __hip_bfloat16* dst;
    int bid = blockIdx.x;
    if (bid < KCONV_BLOCKS) { src = K; dst = Kb; }
    else { src = W; dst = Wb; bid -= KCONV_BLOCKS; }
    int base = (bid * 256 + threadIdx.x) * 8;
    float4 f0 = *(const float4*)(src + base);
    float4 f1 = *(const float4*)(src + base + 4);
    uint4 u;
    u.x = pack_bf2(f0.x, f0.y);
    u.y = pack_bf2(f0.z, f0.w);
    u.z = pack_bf2(f1.x, f1.y);
    u.w = pack_bf2(f1.z, f1.w);
    *(uint4*)(dst + base) = u;
}

// Standalone W conversion for the mid-tier fallback (no Kb space).
__global__ __launch_bounds__(256)
void wconv_kernel(const float* __restrict__ W, __hip_bfloat16* __restrict__ Wb) {
    int base = (blockIdx.x * 256 + threadIdx.x) * 8;
    float4 f0 = *(const float4*)(W + base);
    float4 f1 = *(const float4*)(W + base + 4);
    uint4 u;
    u.x = pack_bf2(f0.x, f0.y);
    u.y = pack_bf2(f0.z, f0.w);
    u.z = pack_bf2(f1.x, f1.y);
    u.w = pack_bf2(f1.z, f1.w);
    *(uint4*)(Wb + base) = u;
}

// ---------------------------------------------------------------------------
// Prep: V [b][n][h*64+d] f32 -> V^T bf16 [b][h][d=64][n=2048]. One 64(n)x64(d)
// tile per block, LDS transpose (padded, one-time cost ~10us total).
// ---------------------------------------------------------------------------
__global__ __launch_bounds__(256)
void vtrans_kernel(const float* __restrict__ v, __hip_bfloat16* __restrict__ vt) {
    __shared__ short T[64][72];   // [d][n], +8 pad
    const int b = blockIdx.z, h = blockIdx.y, n0 = blockIdx.x * 64;
    const int t = threadIdx.x;
    const int ir = t >> 4;            // n-row within pass
    const int d4 = (t & 15) * 4;
#pragma unroll
    for (int pass = 0; pass < 4; ++pass) {
        int n = pass * 16 + ir;
        float4 f = *(const float4*)(v + ((size_t)b * Nv + n0 + n) * Dv + h * DHv + d4);
        T[d4 + 0][n] = (short)(pack_bf2(f.x, f.x) & 0xffffu);
        T[d4 + 1][n] = (short)(pack_bf2(f.y, f.y) & 0xffffu);
        T[d4 + 2][n] = (short)(pack_bf2(f.z, f.z) & 0xffffu);
        T[d4 + 3][n] = (short)(pack_bf2(f.w, f.w) & 0xffffu);
    }
    __syncthreads();
    const int d = t >> 2, kg = (t & 3) * 16;
    unsigned u[8];
#pragma unroll
    for (int i = 0; i < 8; ++i)
        u[i] = (unsigned)(unsigned short)T[d][kg + 2 * i] |
               ((unsigned)(unsigned short)T[d][kg + 2 * i + 1] << 16);
    __hip_bfloat16* op = vt + ((size_t)(b * Hv + h) * DHv + d) * Nv + n0 + kg;
    *(uint4*)op = *(uint4*)&u[0];
    *(uint4*)(op + 8) = *(uint4*)&u[4];
}

// ---------------------------------------------------------------------------
// MFMA flash attention, prep-fed. Block = 256 thr (4 waves) = 128 queries of
// one (b,h). Q frags in registers (from f32 global, once). K and V^T tiles
// staged via global_load_lds w16 from bf16 prep buffers: LDS linear, source
// addr carries inverse XOR swizzle (group ^= row&7), ds_read applies same
// XOR -> balanced banks, zero staging VALU. Double-buffered, one barrier per
// 64-key tile; tile i+1 loads issued before compute of tile i.
// XCD swizzle: the 16 q-tile blocks of one (b,h) map to one XCD.
// ---------------------------------------------------------------------------
__global__ __launch_bounds__(256)
void attn_mfma_pre(const float* __restrict__ q,
                   const __hip_bfloat16* __restrict__ Kb,
                   const __hip_bfloat16* __restrict__ Vtb,
                   __hip_bfloat16* __restrict__ out) {
    __shared__ __align__(16) short Kt[2][64 * 64];   // 16 KB
    __shared__ __align__(16) short Vt[2][64 * 64];   // 16 KB (V^T: rows = d)

    const int t = threadIdx.x;
    const int wave = t >> 6, lane = t & 63;
    const int quad = lane >> 4, lr = lane & 15;
    const int b = blockIdx.z;
    // bijective XCD swizzle over (qtile,head): physical lid2 % 8 ~ XCD.
    const int lid2 = blockIdx.y * 16 + blockIdx.x;   // 0..255
    const int xcd = lid2 & 7, jj = lid2 >> 3;        // jj 0..31
    const int h = xcd * 2 + (jj >> 4);               // same-h -> same XCD
    const int q0 = (jj & 15) * 128;
    const size_t qbh = ((size_t)b * Nv) * Dv + h * DHv;
    const __hip_bfloat16* kb = Kb + (size_t)b * Nv * Dv + h * DHv;
    const __hip_bfloat16* vtb = Vtb + (size_t)(b * Hv + h) * DHv * Nv;

    const int srow = lane >> 3;   // row within 8-row chunk
    const int sg = lane & 7;      // stored group
    auto stage = [&](int buf, int k0) {
#pragma unroll
        for (int c = 0; c < 2; ++c) {
            int blk = wave * 2 + c;          // 0..7, wave-uniform
            int r = blk * 8 + srow;
            int g = sg ^ (r & 7);            // inverse swizzle on source
            __builtin_amdgcn_global_load_lds(
                (const __attribute__((address_space(1))) unsigned*)(const void*)
                    (kb + (size_t)(k0 + r) * Dv + g * 8),
                (__attribute__((address_space(3))) unsigned*)(void*)&Kt[buf][blk * 512],
                16, 0, 0);
            __builtin_amdgcn_global_load_lds(
                (const __attribute__((address_space(1))) unsigned*)(const void*)
                    (vtb + (size_t)r * Nv + k0 + g * 8),
                (__attribute__((address_space(3))) unsigned*)(void*)&Vt[buf][blk * 512],
                16, 0, 0);
        }
    };

    stage(0, 0);   // K/V tile-0 DMA in flight first

    // ---- Q fragments direct from global (once), scale 0.125 exact ----
    short8 qfrag[2][2];   // [qs][kh]: Q[q = q0+w*32+qs*16+lr][d = 32kh+8quad+j]
#pragma unroll
    for (int qs = 0; qs < 2; ++qs)
#pragma unroll
        for (int kh = 0; kh < 2; ++kh) {
            int row = q0 + wave * 32 + qs * 16 + lr;
            const float* qp = q + qbh + (size_t)row * Dv + kh * 32 + quad * 8;
            float4 f0 = *(const float4*)qp;
            float4 f1 = *(const float4*)(qp + 4);
            int4 qi;
            qi.x = (int)pack_bf2(f0.x * 0.125f, f0.y * 0.125f);
            qi.y = (int)pack_bf2(f0.z * 0.125f, f0.w * 0.125f);
            qi.z = (int)pack_bf2(f1.x * 0.125f, f1.y * 0.125f);
            qi.w = (int)pack_bf2(f1.z * 0.125f, f1.w * 0.125f);
            qfrag[qs][kh] = __builtin_bit_cast(short8, qi);
        }

    floatx4 o_acc[2][4] = {};        // [qs][td]: O[q=4quad+r][d=16td+lr]
    float mrow[2] = {-INFINITY, -INFINITY};
    float lrow[2] = {0.f, 0.f};
    const int srcA = ((2 * (quad & 1)) << 4) | lr;   // P-gather source lanes
    const int srcB = srcA + 16;
    const bool hi = (quad >= 2);

    for (int it = 0; it < NT; ++it) {
        const int cur = it & 1;
        __syncthreads();                         // vmcnt drained: buf[cur] staged
        if (it + 1 < NT) stage(1 - cur, (it + 1) * 64);   // latency hidden by compute

        // ---- S^T = K·Q^T ----
        floatx4 s_acc[2][4] = {};
#pragma unroll
        for (int tt = 0; tt < 4; ++tt) {
            int row = tt * 16 + lr;
            short8 kf0 = *(const short8*)&Kt[cur][row * 64 + ((quad ^ (lr & 7)) << 3)];
            short8 kf1 = *(const short8*)&Kt[cur][row * 64 + (((4 + quad) ^ (lr & 7)) << 3)];
#pragma unroll
            for (int qs = 0; qs < 2; ++qs) {
                s_acc[qs][tt] = __builtin_amdgcn_mfma_f32_16x16x32_bf16(kf0, qfrag[qs][0], s_acc[qs][tt], 0, 0, 0);
                s_acc[qs][tt] = __builtin_amdgcn_mfma_f32_16x16x32_bf16(kf1, qfrag[qs][1], s_acc[qs][tt], 0, 0, 0);
            }
        }

        // ---- online softmax + P pack ----
        unsigned p2[2][8];
#pragma unroll
        for (int qs = 0; qs < 2; ++qs) {
            float tmax = -INFINITY;
#pragma unroll
            for (int tt = 0; tt < 4; ++tt)
#pragma unroll
                for (int r2 = 0; r2 < 4; ++r2) tmax = fmaxf(tmax, s_acc[qs][tt][r2]);
            tmax = fmaxf(tmax, __shfl_xor(tmax, 16));
            tmax = fmaxf(tmax, __shfl_xor(tmax, 32));
            float mnew = fmaxf(mrow[qs], tmax);
            float alpha = __expf(mrow[qs] - mnew);   // first tile: exp(-inf)=0
            mrow[qs] = mnew;
            float psum = 0.f;
#pragma unroll
            for (int tt = 0; tt < 4; ++tt)
#pragma unroll
                for (int r2 = 0; r2 < 4; ++r2) {
                    float p = __expf(s_acc[qs][tt][r2] - mnew);
                    s_acc[qs][tt][r2] = p;
                    psum += p;
                }
            psum += __shfl_xor(psum, 16);
            psum += __shfl_xor(psum, 32);
            lrow[qs] = lrow[qs] * alpha + psum;
#pragma unroll
            for (int r2 = 0; r2 < 4; ++r2) {
                float ar = __shfl(alpha, quad * 4 + r2);
#pragma unroll
                for (int td = 0; td < 4; ++td) o_acc[qs][td][r2] *= ar;
            }
#pragma unroll
            for (int tt = 0; tt < 4; ++tt) {
                p2[qs][tt * 2 + 0] = pack_bf2(s_acc[qs][tt][0], s_acc[qs][tt][1]);
                p2[qs][tt * 2 + 1] = pack_bf2(s_acc[qs][tt][2], s_acc[qs][tt][3]);
            }
        }

        // ---- PV: O += P·V ----
#pragma unroll
        for (int kh = 0; kh < 2; ++kh) {
            short8 af[2];
#pragma unroll
            for (int qs = 0; qs < 2; ++qs) {
                int tlo = 4 * kh, thi = 4 * kh + 2;
                unsigned d0a = __shfl(p2[qs][tlo + 0], srcA), d0b = __shfl(p2[qs][thi + 0], srcA);
                unsigned d1a = __shfl(p2[qs][tlo + 1], srcA), d1b = __shfl(p2[qs][thi + 1], srcA);
                unsigned d2a = __shfl(p2[qs][tlo + 0], srcB), d2b = __shfl(p2[qs][thi + 0], srcB);
                unsigned d3a = __shfl(p2[qs][tlo + 1], srcB), d3b = __shfl(p2[qs][thi + 1], srcB);
                int4 afi;
                afi.x = (int)(hi ? d0b : d0a);
                afi.y = (int)(hi ? d1b : d1a);
                afi.z = (int)(hi ? d2b : d2a);
                afi.w = (int)(hi ? d3b : d3a);
                af[qs] = __builtin_bit_cast(short8, afi);
            }
#pragma unroll
            for (int td = 0; td < 4; ++td) {
                int d = td * 16 + lr;
                short8 vf = *(const short8*)&Vt[cur][d * 64 + (((kh * 4 + quad) ^ (lr & 7)) << 3)];
                o_acc[0][td] = __builtin_amdgcn_mfma_f32_16x16x32_bf16(af[0], vf, o_acc[0][td], 0, 0, 0);
                o_acc[1][td] = __builtin_amdgcn_mfma_f32_16x16x32_bf16(af[1], vf, o_acc[1][td], 0, 0, 0);
            }
        }
    }

    // ---- epilogue: O / l -> bf16 ws (proj A-matrix) ----
#pragma unroll
    for (int qs = 0; qs < 2; ++qs) {
        float linv = 1.f / lrow[qs];
#pragma unroll
        for (int r2 = 0; r2 < 4; ++r2) {
            float lv = __shfl(linv, quad * 4 + r2);
            int row = q0 + wave * 32 + qs * 16 + quad * 4 + r2;
            size_t base = ((size_t)(b * Nv + row)) * Dv + h * DHv;
#pragma unroll
            for (int td = 0; td < 4; ++td)
                out[base + td * 16 + lr] = __float2bfloat16(o_acc[qs][td][r2] * lv);
        }
    }
}

// ---------------------------------------------------------------------------
// Fallback MFMA flash attention (R6/R8 known-good): in-kernel f32 K/V load +
// pack + swizzled ds_write staging. Used when ws can't fit Kb/Vtb.
// ---------------------------------------------------------------------------
__global__ __launch_bounds__(256)
void attn_mfma(const float* __restrict__ q,
               const float* __restrict__ k,
               const float* __restrict__ v,
               __hip_bfloat16* __restrict__ out) {
    __shared__ __align__(16) short Kt[2][64 * 64];   // 16 KB
    __shared__ __align__(16) short Vt[2][64 * 64];   // 16 KB (V^T: rows = d)

    const int t = threadIdx.x;
    const int wave = t >> 6, lane = t & 63;
    const int quad = lane >> 4, lr = lane & 15;
    const int b = blockIdx.z, h = blockIdx.y;
    const int q0 = blockIdx.x * 128;
    const size_t bh = ((size_t)b * Nv) * Dv + h * DHv;

    float4 kpre[2][2], vpre[2][2];
    auto load_tile = [&](int k0) {
#pragma unroll
        for (int p = 0; p < 2; ++p) {
            int idx = p * 256 + t;
            int r = idx >> 3, cb = idx & 7;
            const float* kp = k + bh + (size_t)(k0 + r) * Dv + cb * 8;
            kpre[p][0] = *(const float4*)kp;
            kpre[p][1] = *(const float4*)(kp + 4);
            int dq = idx & 15, rr = idx >> 4;
            const float* vp = v + bh + (size_t)(k0 + 2 * rr) * Dv + dq * 4;
            vpre[p][0] = *(const float4*)vp;
            vpre[p][1] = *(const float4*)(vp + Dv);
        }
    };
    auto store_tile = [&](int buf) {
#pragma unroll
        for (int p = 0; p < 2; ++p) {
            int idx = p * 256 + t;
            int r = idx >> 3, cb = idx & 7;
            uint4 u;
            u.x = pack_bf2(kpre[p][0].x, kpre[p][0].y);
            u.y = pack_bf2(kpre[p][0].z, kpre[p][0].w);
            u.z = pack_bf2(kpre[p][1].x, kpre[p][1].y);
            u.w = pack_bf2(kpre[p][1].z, kpre[p][1].w);
            *(uint4*)&Kt[buf][r * 64 + ((cb ^ (r & 7)) << 3)] = u;
            int dq = idx & 15, rr = idx >> 4;
            float va[4] = {vpre[p][0].x, vpre[p][0].y, vpre[p][0].z, vpre[p][0].w};
            float vb[4] = {vpre[p][1].x, vpre[p][1].y, vpre[p][1].z, vpre[p][1].w};
#pragma unroll
            for (int i = 0; i < 4; ++i) {
                int d = dq * 4 + i;
                ((unsigned*)Vt[buf])[d * 32 + (((rr >> 2) ^ ((d >> 1) & 7)) << 2) + (rr & 3)] =
                    pack_bf2(va[i], vb[i]);
            }
        }
    };

    load_tile(0);

    short8 qfrag[2][2];
#pragma unroll
    for (int qs = 0; qs < 2; ++qs)
#pragma unroll
        for (int kh = 0; kh < 2; ++kh) {
            int row = q0 + wave * 32 + qs * 16 + lr;
            const float* qp = q + bh + (size_t)row * Dv + kh * 32 + quad * 8;
            float4 f0 = *(const float4*)qp;
            float4 f1 = *(const float4*)(qp + 4);
            int4 qi;
            qi.x = (int)pack_bf2(f0.x * 0.125f, f0.y * 0.125f);
            qi.y = (int)pack_bf2(f0.z * 0.125f, f0.w * 0.125f);
            qi.z = (int)pack_bf2(f1.x * 0.125f, f1.y * 0.125f);
            qi.w = (int)pack_bf2(f1.z * 0.125f, f1.w * 0.125f);
            qfrag[qs][kh] = __builtin_bit_cast(short8, qi);
        }

    store_tile(0);

    floatx4 o_acc[2][4] = {};
    float mrow[2] = {-INFINITY, -INFINITY};
    float lrow[2] = {0.f, 0.f};
    const int srcA = ((2 * (quad & 1)) << 4) | lr;
    const int srcB = srcA + 16;
    const bool hi = (quad >= 2);

    for (int it = 0; it < NT; ++it) {
        const int cur = it & 1;
        __syncthreads();
        if (it + 1 < NT) load_tile((it + 1) * 64);

        floatx4 s_acc[2][4] = {};
#pragma unroll
        for (int tt = 0; tt < 4; ++tt) {
            int row = tt * 16 + lr;
            short8 kf0 = *(const short8*)&Kt[cur][row * 64 + ((quad ^ (lr & 7)) << 3)];
            short8 kf1 = *(const short8*)&Kt[cur][row * 64 + (((4 + quad) ^ (lr & 7)) << 3)];
#pragma unroll
            for (int qs = 0; qs < 2; ++qs) {
                s_acc[qs][tt] = __builtin_amdgcn_mfma_f32_16x16x32_bf16(kf0, qfrag[qs][0], s_acc[qs][tt], 0, 0, 0);
                s_acc[qs][tt] = __builtin_amdgcn_mfma_f32_16x16x32_bf16(kf1, qfrag[qs][1], s_acc[qs][tt], 0, 0, 0);
            }
        }

        unsigned p2[2][8];
#pragma unroll
        for (int qs = 0; qs < 2; ++qs) {
            float tmax = -INFINITY;
#pragma unroll
            for (int tt = 0; tt < 4; ++tt)
#pragma unroll
                for (int r2 = 0; r2 < 4; ++r2) tmax = fmaxf(tmax, s_acc[qs][tt][r2]);
            tmax = fmaxf(tmax, __shfl_xor(tmax, 16));
            tmax = fmaxf(tmax, __shfl_xor(tmax, 32));
            float mnew = fmaxf(mrow[qs], tmax);
            float alpha = __expf(mrow[qs] - mnew);
            mrow[qs] = mnew;
            float psum = 0.f;
#pragma unroll
            for (int tt = 0; tt < 4; ++tt)
#pragma unroll
                for (int r2 = 0; r2 < 4; ++r2) {
                    float p = __expf(s_acc[qs][tt][r2] - mnew);
                    s_acc[qs][tt][r2] = p;
                    psum += p;
                }
            psum += __shfl_xor(psum, 16);
            psum += __shfl_xor(psum, 32);
            lrow[qs] = lrow[qs] * alpha + psum;
#pragma unroll
            for (int r2 = 0; r2 < 4; ++r2) {
                float ar = __shfl(alpha, quad * 4 + r2);
#pragma unroll
                for (int td = 0; td < 4; ++td) o_acc[qs][td][r2] *= ar;
            }
#pragma unroll
            for (int tt = 0; tt < 4; ++tt) {
                p2[qs][tt * 2 + 0] = pack_bf2(s_acc[qs][tt][0], s_acc[qs][tt][1]);
                p2[qs][tt * 2 + 1] = pack_bf2(s_acc[qs][tt][2], s_acc[qs][tt][3]);
            }
        }

#pragma unroll
        for (int kh = 0; kh < 2; ++kh) {
            short8 af[2];
#pragma unroll
            for (int qs = 0; qs < 2; ++qs) {
                int tlo = 4 * kh, thi = 4 * kh + 2;
                unsigned d0a = __shfl(p2[qs][tlo + 0], srcA), d0b = __shfl(p2[qs][thi + 0], srcA);
                unsigned d1a = __shfl(p2[qs][tlo + 1], srcA), d1b = __shfl(p2[qs][thi + 1], srcA);
                unsigned d2a = __shfl(p2[qs][tlo + 0], srcB), d2b = __shfl(p2[qs][thi + 0], srcB);
                unsigned d3a = __shfl(p2[qs][tlo + 1], srcB), d3b = __shfl(p2[qs][thi + 1], srcB);
                int4 afi;
                afi.x = (int)(hi ? d0b : d0a);
                afi.y = (int)(hi ? d1b : d1a);
                afi.z = (int)(hi ? d2b : d2a);
                afi.w = (int)(hi ? d3b : d3a);
                af[qs] = __builtin_bit_cast(short8, afi);
            }
#pragma unroll
            for (int td = 0; td < 4; ++td) {
                int d = td * 16 + lr;
                short8 vf = *(const short8*)&Vt[cur][d * 64 + (((kh * 4 + quad) ^ (lr >> 1)) << 3)];
                o_acc[0][td] = __builtin_amdgcn_mfma_f32_16x16x32_bf16(af[0], vf, o_acc[0][td], 0, 0, 0);
                o_acc[1][td] = __builtin_amdgcn_mfma_f32_16x16x32_bf16(af[1], vf, o_acc[1][td], 0, 0, 0);
            }
        }

        if (it + 1 < NT) store_tile(1 - cur);
    }

#pragma unroll
    for (int qs = 0; qs < 2; ++qs) {
        float linv = 1.f / lrow[qs];
#pragma unroll
        for (int r2 = 0; r2 < 4; ++r2) {
            float lv = __shfl(linv, quad * 4 + r2);
            int row = q0 + wave * 32 + qs * 16 + quad * 4 + r2;
            size_t base = ((size_t)(b * Nv + row)) * Dv + h * DHv;
#pragma unroll
            for (int td = 0; td < 4; ++td)
                out[base + td * 16 + lr] = __float2bfloat16(o_acc[qs][td][r2] * lv);
        }
    }
}

// ---------------------------------------------------------------------------
// Stage 2: C = A @ Wb^T. m97-structure: 128x128 tile, BK=64, double-buffered
// LDS, global_load_lds w16, XOR-swizzled (row&7) 128B rows. XCD swizzle: the
// 8 blocks sharing an A-panel (same bm) map to one XCD (nwg=512, 512%8==0).
// ---------------------------------------------------------------------------
__global__ __launch_bounds__(256)
void proj_kernel(const __hip_bfloat16* __restrict__ A,
                 const __hip_bfloat16* __restrict__ Wb,
                 float* __restrict__ C) {
    __shared__ __align__(16) short As[2][128 * 64];  // 32 KB
    __shared__ __align__(16) short Ws[2][128 * 64];  // 32 KB

    const int t = threadIdx.x;
    const int wave = t >> 6, lane = t & 63;
    const int quad = lane >> 4, lr = lane & 15;
    const int wm = wave >> 1, wn = wave & 1;
    // XCD swizzle: lid%8 ~ XCD; same-bm blocks share one XCD's L2.
    const int lid = blockIdx.y * 8 + blockIdx.x;     // 0..511 (grid 8x64)
    const int xcd = lid & 7, j = lid >> 3;
    const int bm = (xcd * 8 + (j >> 3)) * 128;
    const int bn = (j & 7) * 128;

    floatx4 acc[4][4] = {};   // [mb][nb]

    auto stage = [&](int buf, int k0) {
#pragma unroll
        for (int c = 0; c < 4; ++c) {
            const int blk = c * 4 + wave;             // 0..15, wave-uniform
            const int r = blk * 8 + (lane >> 3);
            const int g = (lane & 7) ^ (r & 7);
            const __hip_bfloat16* ga = A + (size_t)(bm + r) * Dv + k0 + g * 8;
            const __hip_bfloat16* gw = Wb + (size_t)(bn + r) * Dv + k0 + g * 8;
            __builtin_amdgcn_global_load_lds(
                (const __attribute__((address_space(1))) unsigned int*)(const void*)ga,
                (__attribute__((address_space(3))) unsigned int*)(void*)&As[buf][blk * 512],
                16, 0, 0);
            __builtin_amdgcn_global_load_lds(
                (const __attribute__((address_space(1))) unsigned int*)(const void*)gw,
                (__attribute__((address_space(3))) unsigned int*)(void*)&Ws[buf][blk * 512],
                16, 0, 0);
        }
    };

    stage(0, 0);

    for (int it = 0; it < Dv / 64; ++it) {
        const int cur = it & 1;
        __syncthreads();                              // drains vmcnt: buf[cur] staged
        if (it + 1 < Dv / 64) stage(1 - cur, (it + 1) * 64);   // overlaps compute

#pragma unroll
        for (int ks = 0; ks < 2; ++ks) {
            short8 af[4];
#pragma unroll
            for (int mb = 0; mb < 4; ++mb) {
                int row = wm * 64 + mb * 16 + lr;
                af[mb] = *(const short8*)&As[cur][row * 64 + (((ks * 4 + quad) ^ (lr & 7)) << 3)];
            }
#pragma unroll
            for (int nb = 0; nb < 4; ++nb) {
                int row = wn * 64 + nb * 16 + lr;
                short8 bf = *(const short8*)&Ws[cur][row * 64 + (((ks * 4 + quad) ^ (lr & 7)) << 3)];
#pragma unroll
                for (int mb = 0; mb < 4; ++mb)
                    acc[mb][nb] = __builtin_amdgcn_mfma_f32_16x16x32_bf16(af[mb], bf, acc[mb][nb], 0, 0, 0);
            }
        }
    }

    // C/D layout: col = lane&15, row = quad*4 + reg
#pragma unroll
    for (int mb = 0; mb < 4; ++mb)
#pragma unroll
        for (int nb = 0; nb < 4; ++nb) {
            int row = bm + wm * 64 + mb * 16 + quad * 4;
            int col = bn + wn * 64 + nb * 16 + lr;
#pragma unroll
            for (int r = 0; r < 4; ++r)
                C[(size_t)(row + r) * Dv + col] = acc[mb][nb][r];
        }
}

// ---------------------------------------------------------------------------
// Stage 2 (fallback, R6 known-good): f32 W, in-kernel pack, BK=32.
// ---------------------------------------------------------------------------
__global__ __launch_bounds__(256)
void proj_kernel_f32w(const __hip_bfloat16* __restrict__ A,
                      const float* __restrict__ W,
                      float* __restrict__ C) {
    __shared__ __align__(16) short As[2][128 * 32];
    __shared__ __align__(16) short Ws[2][128 * 32];

    const int t = threadIdx.x;
    const int wave = t >> 6, lane = t & 63;
    const int quad = lane >> 4, lr = lane & 15;
    const int wm = wave >> 1, wn = wave & 1;
    const int bm = blockIdx.y * 128;
    const int bn = blockIdx.x * 128;

    floatx4 acc[4][4] = {};

    const int rA = t >> 2;
    const int cbA = t & 3;

    uint4 apre[2];
    float4 wpre[2][2];
    auto load_t = [&](int k0) {
#pragma unroll
        for (int p = 0; p < 2; ++p) {
            int r = rA + p * 64;
            apre[p] = *(const uint4*)(A + (size_t)(bm + r) * Dv + k0 + cbA * 8);
            const float* wp = W + (size_t)(bn + r) * Dv + k0 + cbA * 8;
            wpre[p][0] = *(const float4*)wp;
            wpre[p][1] = *(const float4*)(wp + 4);
        }
    };
    auto store_t = [&](int buf) {
#pragma unroll
        for (int p = 0; p < 2; ++p) {
            int r = rA + p * 64;
            *(uint4*)&As[buf][r * 32 + cbA * 8] = apre[p];
            uint4 u;
            u.x = pack_bf2(wpre[p][0].x, wpre[p][0].y);
            u.y = pack_bf2(wpre[p][0].z, wpre[p][0].w);
            u.z = pack_bf2(wpre[p][1].x, wpre[p][1].y);
            u.w = pack_bf2(wpre[p][1].z, wpre[p][1].w);
            *(uint4*)&Ws[buf][r * 32 + cbA * 8] = u;
        }
    };

    load_t(0);
    store_t(0);

    for (int it = 0; it < Dv / 32; ++it) {
        const int cur = it & 1;
        __syncthreads();
        if (it + 1 < Dv / 32) load_t((it + 1) * 32);

        short8 af[4];
#pragma unroll
        for (int mb = 0; mb < 4; ++mb)
            af[mb] = *(const short8*)&As[cur][(wm * 64 + mb * 16 + lr) * 32 + quad * 8];
#pragma unroll
        for (int nb = 0; nb < 4; ++nb) {
            short8 bf = *(const short8*)&Ws[cur][(wn * 64 + nb * 16 + lr) * 32 + quad * 8];
#pragma unroll
            for (int mb = 0; mb < 4; ++mb)
                acc[mb][nb] = __builtin_amdgcn_mfma_f32_16x16x32_bf16(af[mb], bf, acc[mb][nb], 0, 0, 0);
        }

        if (it + 1 < Dv / 32) store_t(1 - cur);
    }

#pragma unroll
    for (int mb = 0; mb < 4; ++mb)
#pragma unroll
        for (int nb = 0; nb < 4; ++nb) {
            int row = bm + wm * 64 + mb * 16 + quad * 4;
            int col = bn + wn * 64 + nb * 16 + lr;
#pragma unroll
            for (int r = 0; r < 4; ++r)
                C[(size_t)(row + r) * Dv + col] = acc[mb][nb][r];
        }
}

// ---------------------------------------------------------------------------
// Stage 3: LayerNorm in place on d_out (fp32). Biased variance, eps=1e-5.
// ---------------------------------------------------------------------------
__global__ __launch_bounds__(256)
void ln_kernel(float* __restrict__ C,
               const float* __restrict__ g) {
    const int row = blockIdx.x;
    const int t = threadIdx.x;
    const int wave = t >> 6, lane = t & 63;

    float* rp = C + (size_t)row * Dv;
    float4 x = *(const float4*)(rp + t * 4);

    float s = x.x + x.y + x.z + x.w;
    float sq = x.x * x.x + x.y * x.y + x.z * x.z + x.w * x.w;
#pragma unroll
    for (int off = 32; off >= 1; off >>= 1) {
        s += __shfl_xor(s, off);
        sq += __shfl_xor(sq, off);
    }
    __shared__ float ss[4], ssq[4];
    if (lane == 0) { ss[wave] = s; ssq[wave] = sq; }
    __syncthreads();
    s = ss[0] + ss[1] + ss[2] + ss[3];
    sq = ssq[0] + ssq[1] + ssq[2] + ssq[3];

    const float rn = 1.f / (float)Dv;
    float mean = s * rn;
    float var = sq * rn - mean * mean;
    float inv = rsqrtf(var + 1e-5f);

    float4 gv = *(const float4*)(g + t * 4);

    float4 o;
    o.x = (x.x - mean) * inv * gv.x;
    o.y = (x.y - mean) * inv * gv.y;
    o.z = (x.z - mean) * inv * gv.z;
    o.w = (x.w - mean) * inv * gv.w;
    *(float4*)(rp + t * 4) = o;
}

// ---------------------------------------------------------------------------
extern "C" void kernel_launch(void* const* d_in, const int* in_sizes, int n_in,
                              void* d_out, int out_size, void* d_ws, size_t ws_size,
                              hipStream_t stream) {
    const float* q = (const float*)d_in[0];
    const float* k = (const float*)d_in[1];
    const float* v = (const float*)d_in[2];
    const float* W = (const float*)d_in[3];
    const float* g = (const float*)d_in[4];
    float* out = (float*)d_out;

    const size_t attnB = (size_t)Bv * Nv * Dv * 2;       // 16 MiB bf16 attn out
    const size_t wbB = (size_t)Dv * Dv * 2;              // 2 MiB bf16 W
    const size_t kbB = (size_t)Bv * Nv * Dv * 2;         // 16 MiB bf16 K
    const size_t vtB = (size_t)Bv * Hv * DHv * Nv * 2;   // 16 MiB bf16 V^T

    __hip_bfloat16* attn = (__hip_bfloat16*)d_ws;

    if (ws_size >= attnB + wbB + kbB + vtB) {
        __hip_bfloat16* Wb = (__hip_bfloat16*)((char*)d_ws + attnB);
        __hip_bfloat16* Kb = (__hip_bfloat16*)((char*)d_ws + attnB + wbB);
        __hip_bfloat16* Vtb = (__hip_bfloat16*)((char*)d_ws + attnB + wbB + kbB);
        prep_conv<<<KCONV_BLOCKS + WCONV_BLOCKS, 256, 0, stream>>>(k, Kb, W, Wb);
        vtrans_kernel<<<dim3(Nv / 64, Hv, Bv), 256, 0, stream>>>(v, Vtb);
        attn_mfma_pre<<<dim3(16, 16, Bv), 256, 0, stream>>>(q, Kb, Vtb, attn);
        proj_kernel<<<dim3(Dv / 128, (Bv * Nv) / 128), 256, 0, stream>>>(attn, Wb, out);
    } else if (ws_size >= attnB + wbB) {
        __hip_bfloat16* Wb = (__hip_bfloat16*)((char*)d_ws + attnB);
        wconv_kernel<<<WCONV_BLOCKS, 256, 0, stream>>>(W, Wb);
        attn_mfma<<<dim3(Nv / 128, Hv, Bv), 256, 0, stream>>>(q, k, v, attn);
        proj_kernel<<<dim3(Dv / 128, (Bv * Nv) / 128), 256, 0, stream>>>(attn, Wb, out);
    } else {
        attn_mfma<<<dim3(Nv / 128, Hv, Bv), 256, 0, stream>>>(q, k, v, attn);
        proj_kernel_f32w<<<dim3(Dv / 128, (Bv * Nv) / 128), 256, 0, stream>>>(attn, W, out);
    }

    ln_kernel<<<Bv * Nv, 256, 0, stream>>>(out, g);
}

// Round 5
// 317.742 us; speedup vs baseline: 1.0733x; 1.0733x over previous
//
#include <hip/hip_runtime.h>
#include <hip/hip_bf16.h>

// Problem: B=4, N=2048, H=16, Dh=64, D=1024. All global tensors fp32.
// out = LN( softmax(Q K^T / 8) V @ W_out^T ) * g   (fp32 out).
// R11 = R10 resubmit with permlane builtins instead of raw asm (R4 bench died
// at container level; builtins de-risk the only new mechanism).
// attn: cross-lane softmax/P-gather via v_permlane{16,32}_swap_b32:
//   swap32(a,b): a'=[a.lo32,b.lo32] b'=[a.hi32,b.hi32]
//   swap16(a,b): a'=[a.r0,b.r0,a.r2,b.r2] b'=[a.r1,b.r1,a.r3,b.r3]
//   For P pair (x,y)=(p2[tlo+i],p2[thi+i]): swap32 then swap16 gives
//   a''=[x0,x2,y0,y2] b''=[x1,x3,y1,y3] == the old srcA/srcB cndmask words.
// Quad reduces: self-swap + op (commutative -> bit-identical to shfl_xor).
// Prep fused to one launch; proj XCD swizzle reverted (L3-fit data).
// All math bit-identical to R9-verified kernel -> absmax must stay 0.03125.

#define Bv 4
#define Nv 2048
#define Hv 16
#define DHv 64
#define Dv 1024
#define NT (Nv / 64)

#define KCONV_BLOCKS 4096
#define WCONV_BLOCKS 512
#define VT_BLOCKS 2048

typedef __attribute__((ext_vector_type(8))) short short8;
typedef __attribute__((ext_vector_type(4))) float floatx4;

// bf16 pair pack, round-half-up (+0x8000 then take high16 via one v_perm_b32).
__device__ inline unsigned pack_bf2(float a, float b) {
    unsigned ua = __builtin_bit_cast(unsigned, a) + 0x8000u;
    unsigned ub = __builtin_bit_cast(unsigned, b) + 0x8000u;
    return __builtin_amdgcn_perm(ub, ua, 0x07060302u);  // [b.hi16 : a.hi16]
}

__device__ inline void plswap16(unsigned &a, unsigned &b) {
    auto r = __builtin_amdgcn_permlane16_swap(a, b, false, false);
    a = r[0]; b = r[1];
}
__device__ inline void plswap32(unsigned &a, unsigned &b) {
    auto r = __builtin_amdgcn_permlane32_swap(a, b, false, false);
    a = r[0]; b = r[1];
}

// Cross-quad reduce via permlane self-swap: stage1 == shfl_xor 16,
// stage2 == shfl_xor 32. fmax/add commutative -> bit-identical values.
__device__ inline float redq_max(float x) {
    unsigned a = __builtin_bit_cast(unsigned, x), b = a;
    plswap16(a, b);
    float m = fmaxf(__builtin_bit_cast(float, a), __builtin_bit_cast(float, b));
    unsigned c = __builtin_bit_cast(unsigned, m), d = c;
    plswap32(c, d);
    return fmaxf(__builtin_bit_cast(float, c), __builtin_bit_cast(float, d));
}
__device__ inline float redq_sum(float x) {
    unsigned a = __builtin_bit_cast(unsigned, x), b = a;
    plswap16(a, b);
    float m = __builtin_bit_cast(float, a) + __builtin_bit_cast(float, b);
    unsigned c = __builtin_bit_cast(unsigned, m), d = c;
    plswap32(c, d);
    return __builtin_bit_cast(float, c) + __builtin_bit_cast(float, d);
}

// ---------------------------------------------------------------------------
// Fused prep (one launch): K f32->bf16 (4096 blk), W f32->bf16 (512 blk),
// V f32 -> V^T bf16 [b][h][64][2048] (2048 blk). pack_bf2 rounding keeps all
// downstream operand bits identical to the in-kernel-staging versions.
// ---------------------------------------------------------------------------
__global__ __launch_bounds__(256)
void prep_all(const float* __restrict__ K, __hip_bfloat16* __restrict__ Kb,
              const float* __restrict__ W, __hip_bfloat16* __restrict__ Wb,
              const float* __restrict__ v, __hip_bfloat16* __restrict__ vt) {
    __shared__ short T[64][72];   // vtrans scratch (+8 pad)
    int bid = blockIdx.x;
    if (bid < KCONV_BLOCKS + WCONV_BLOCKS) {
        const float* src;
        __hip_bfloat16* dst;
        if (bid < KCONV_BLOCKS) { src = K; dst = Kb; }
        else { src = W; dst = Wb; bid -= KCONV_BLOCKS; }
        int base = (bid * 256 + threadIdx.x) * 8;
        float4 f0 = *(const float4*)(src + base);
        float4 f1 = *(const float4*)(src + base + 4);
        uint4 u;
        u.x = pack_bf2(f0.x, f0.y);
        u.y = pack_bf2(f0.z, f0.w);
        u.z = pack_bf2(f1.x, f1.y);
        u.w = pack_bf2(f1.z, f1.w);
        *(uint4*)(dst + base) = u;
        return;
    }
    bid -= KCONV_BLOCKS + WCONV_BLOCKS;        // 0..2047
    const int b = bid >> 9;                    // 512 per batch
    const int rem = bid & 511;
    const int h = rem >> 5;                    // 16 heads
    const int n0 = (rem & 31) * 64;            // 32 n-tiles
    const int t = threadIdx.x;
    const int ir = t >> 4;
    const int d4 = (t & 15) * 4;
#pragma unroll
    for (int pass = 0; pass < 4; ++pass) {
        int n = pass * 16 + ir;
        float4 f = *(const float4*)(v + ((size_t)b * Nv + n0 + n) * Dv + h * DHv + d4);
        T[d4 + 0][n] = (short)(pack_bf2(f.x, f.x) & 0xffffu);
        T[d4 + 1][n] = (short)(pack_bf2(f.y, f.y) & 0xffffu);
        T[d4 + 2][n] = (short)(pack_bf2(f.z, f.z) & 0xffffu);
        T[d4 + 3][n] = (short)(pack_bf2(f.w, f.w) & 0xffffu);
    }
    __syncthreads();
    const int d = t >> 2, kg = (t & 3) * 16;
    unsigned u[8];
#pragma unroll
    for (int i = 0; i < 8; ++i)
        u[i] = (unsigned)(unsigned short)T[d][kg + 2 * i] |
               ((unsigned)(unsigned short)T[d][kg + 2 * i + 1] << 16);
    __hip_bfloat16* op = vt + ((size_t)(b * Hv + h) * DHv + d) * Nv + n0 + kg;
    *(uint4*)op = *(uint4*)&u[0];
    *(uint4*)(op + 8) = *(uint4*)&u[4];
}

// ---------------------------------------------------------------------------
// MFMA flash attention, prep-fed. Block = 256 thr (4 waves) = 128 queries of
// one (b,h). Q frags in registers. K / V^T tiles staged via global_load_lds
// w16 (source-side inverse XOR swizzle, LDS linear, read applies same XOR).
// Softmax cross-lane + P-gather done with permlane swaps (VALU pipe).
// ---------------------------------------------------------------------------
__global__ __launch_bounds__(256)
void attn_mfma_pre(const float* __restrict__ q,
                   const __hip_bfloat16* __restrict__ Kb,
                   const __hip_bfloat16* __restrict__ Vtb,
                   __hip_bfloat16* __restrict__ out) {
    __shared__ __align__(16) short Kt[2][64 * 64];   // 16 KB
    __shared__ __align__(16) short Vt[2][64 * 64];   // 16 KB (V^T: rows = d)

    const int t = threadIdx.x;
    const int wave = t >> 6, lane = t & 63;
    const int quad = lane >> 4, lr = lane & 15;
    const int b = blockIdx.z;
    // bijective XCD swizzle over (qtile,head): same-h blocks -> same XCD.
    const int lid2 = blockIdx.y * 16 + blockIdx.x;   // 0..255
    const int xcd = lid2 & 7, jj = lid2 >> 3;        // jj 0..31
    const int h = xcd * 2 + (jj >> 4);
    const int q0 = (jj & 15) * 128;
    const size_t qbh = ((size_t)b * Nv) * Dv + h * DHv;
    const __hip_bfloat16* kb = Kb + (size_t)b * Nv * Dv + h * DHv;
    const __hip_bfloat16* vtb = Vtb + (size_t)(b * Hv + h) * DHv * Nv;

    const int srow = lane >> 3;   // row within 8-row chunk
    const int sg = lane & 7;      // stored group
    auto stage = [&](int buf, int k0) {
#pragma unroll
        for (int c = 0; c < 2; ++c) {
            int blk = wave * 2 + c;          // 0..7, wave-uniform
            int r = blk * 8 + srow;
            int g = sg ^ (r & 7);            // inverse swizzle on source
            __builtin_amdgcn_global_load_lds(
                (const __attribute__((address_space(1))) unsigned*)(const void*)
                    (kb + (size_t)(k0 + r) * Dv + g * 8),
                (__attribute__((address_space(3))) unsigned*)(void*)&Kt[buf][blk * 512],
                16, 0, 0);
            __builtin_amdgcn_global_load_lds(
                (const __attribute__((address_space(1))) unsigned*)(const void*)
                    (vtb + (size_t)r * Nv + k0 + g * 8),
                (__attribute__((address_space(3))) unsigned*)(void*)&Vt[buf][blk * 512],
                16, 0, 0);
        }
    };

    stage(0, 0);   // K/V tile-0 DMA in flight first

    // ---- Q fragments direct from global (once), scale 0.125 exact ----
    short8 qfrag[2][2];   // [qs][kh]: Q[q = q0+w*32+qs*16+lr][d = 32kh+8quad+j]
#pragma unroll
    for (int qs = 0; qs < 2; ++qs)
#pragma unroll
        for (int kh = 0; kh < 2; ++kh) {
            int row = q0 + wave * 32 + qs * 16 + lr;
            const float* qp = q + qbh + (size_t)row * Dv + kh * 32 + quad * 8;
            float4 f0 = *(const float4*)qp;
            float4 f1 = *(const float4*)(qp + 4);
            int4 qi;
            qi.x = (int)pack_bf2(f0.x * 0.125f, f0.y * 0.125f);
            qi.y = (int)pack_bf2(f0.z * 0.125f, f0.w * 0.125f);
            qi.z = (int)pack_bf2(f1.x * 0.125f, f1.y * 0.125f);
            qi.w = (int)pack_bf2(f1.z * 0.125f, f1.w * 0.125f);
            qfrag[qs][kh] = __builtin_bit_cast(short8, qi);
        }

    floatx4 o_acc[2][4] = {};        // [qs][td]: O[q=4quad+r][d=16td+lr]
    float mrow[2] = {-INFINITY, -INFINITY};
    float lrow[2] = {0.f, 0.f};

    for (int it = 0; it < NT; ++it) {
        const int cur = it & 1;
        __syncthreads();                         // vmcnt drained: buf[cur] staged
        if (it + 1 < NT) stage(1 - cur, (it + 1) * 64);   // latency hidden by compute

        // ---- S^T = K·Q^T ----
        floatx4 s_acc[2][4] = {};
#pragma unroll
        for (int tt = 0; tt < 4; ++tt) {
            int row = tt * 16 + lr;
            short8 kf0 = *(const short8*)&Kt[cur][row * 64 + ((quad ^ (lr & 7)) << 3)];
            short8 kf1 = *(const short8*)&Kt[cur][row * 64 + (((4 + quad) ^ (lr & 7)) << 3)];
#pragma unroll
            for (int qs = 0; qs < 2; ++qs) {
                s_acc[qs][tt] = __builtin_amdgcn_mfma_f32_16x16x32_bf16(kf0, qfrag[qs][0], s_acc[qs][tt], 0, 0, 0);
                s_acc[qs][tt] = __builtin_amdgcn_mfma_f32_16x16x32_bf16(kf1, qfrag[qs][1], s_acc[qs][tt], 0, 0, 0);
            }
        }

        // ---- online softmax + P pack (cross-lane via permlane swaps) ----
        unsigned p2[2][8];
#pragma unroll
        for (int qs = 0; qs < 2; ++qs) {
            float t4[4];
#pragma unroll
            for (int tt = 0; tt < 4; ++tt)
                t4[tt] = fmaxf(fmaxf(s_acc[qs][tt][0], s_acc[qs][tt][1]),
                               fmaxf(s_acc[qs][tt][2], s_acc[qs][tt][3]));
            float tmax = fmaxf(fmaxf(t4[0], t4[1]), fmaxf(t4[2], t4[3]));
            tmax = redq_max(tmax);
            float mnew = fmaxf(mrow[qs], tmax);
            float alpha = __expf(mrow[qs] - mnew);   // first tile: exp(-inf)=0
            mrow[qs] = mnew;
            float psum = 0.f;
#pragma unroll
            for (int tt = 0; tt < 4; ++tt)
#pragma unroll
                for (int r2 = 0; r2 < 4; ++r2) {
                    float p = __expf(s_acc[qs][tt][r2] - mnew);
                    s_acc[qs][tt][r2] = p;
                    psum += p;
                }
            psum = redq_sum(psum);
            lrow[qs] = lrow[qs] * alpha + psum;
#pragma unroll
            for (int r2 = 0; r2 < 4; ++r2) {
                float ar = __shfl(alpha, quad * 4 + r2);
#pragma unroll
                for (int td = 0; td < 4; ++td) o_acc[qs][td][r2] *= ar;
            }
#pragma unroll
            for (int tt = 0; tt < 4; ++tt) {
                p2[qs][tt * 2 + 0] = pack_bf2(s_acc[qs][tt][0], s_acc[qs][tt][1]);
                p2[qs][tt * 2 + 1] = pack_bf2(s_acc[qs][tt][2], s_acc[qs][tt][3]);
            }
        }

        // ---- PV: O += P·V.  P-gather per pair (x,y)=(p2[tlo+i],p2[thi+i]):
        // swap32 -> a=[x.lo,y.lo] b=[x.hi,y.hi]; swap16 -> a=[x0,x2,y0,y2]
        // b=[x1,x3,y1,y3] == old srcA/srcB cndmask words. Bit-identical. ----
#pragma unroll
        for (int kh = 0; kh < 2; ++kh) {
            short8 af[2];
#pragma unroll
            for (int qs = 0; qs < 2; ++qs) {
                int tlo = 4 * kh, thi = 4 * kh + 2;
                unsigned a0 = p2[qs][tlo + 0], b0 = p2[qs][thi + 0];
                unsigned a1 = p2[qs][tlo + 1], b1 = p2[qs][thi + 1];
                plswap32(a0, b0);
                plswap16(a0, b0);
                plswap32(a1, b1);
                plswap16(a1, b1);
                int4 afi;
                afi.x = (int)a0;
                afi.y = (int)a1;
                afi.z = (int)b0;
                afi.w = (int)b1;
                af[qs] = __builtin_bit_cast(short8, afi);
            }
#pragma unroll
            for (int td = 0; td < 4; ++td) {
                int d = td * 16 + lr;
                short8 vf = *(const short8*)&Vt[cur][d * 64 + (((kh * 4 + quad) ^ (lr & 7)) << 3)];
                o_acc[0][td] = __builtin_amdgcn_mfma_f32_16x16x32_bf16(af[0], vf, o_acc[0][td], 0, 0, 0);
                o_acc[1][td] = __builtin_amdgcn_mfma_f32_16x16x32_bf16(af[1], vf, o_acc[1][td], 0, 0, 0);
            }
        }
    }

    // ---- epilogue: O / l -> bf16 ws (proj A-matrix) ----
#pragma unroll
    for (int qs = 0; qs < 2; ++qs) {
        float linv = 1.f / lrow[qs];
#pragma unroll
        for (int r2 = 0; r2 < 4; ++r2) {
            float lv = __shfl(linv, quad * 4 + r2);
            int row = q0 + wave * 32 + qs * 16 + quad * 4 + r2;
            size_t base = ((size_t)(b * Nv + row)) * Dv + h * DHv;
#pragma unroll
            for (int td = 0; td < 4; ++td)
                out[base + td * 16 + lr] = __float2bfloat16(o_acc[qs][td][r2] * lv);
        }
    }
}

// ---------------------------------------------------------------------------
// Stage 2: C = A @ Wb^T. m97-structure: 128x128 tile, BK=64, double-buffered
// LDS, global_load_lds w16, XOR-swizzled (row&7) 128B rows. Plain block
// mapping (data is L3-fit; XCD swizzle measured counterproductive here).
// ---------------------------------------------------------------------------
__global__ __launch_bounds__(256)
void proj_kernel(const __hip_bfloat16* __restrict__ A,
                 const __hip_bfloat16* __restrict__ Wb,
                 float* __restrict__ C) {
    __shared__ __align__(16) short As[2][128 * 64];  // 32 KB
    __shared__ __align__(16) short Ws[2][128 * 64];  // 32 KB

    const int t = threadIdx.x;
    const int wave = t >> 6, lane = t & 63;
    const int quad = lane >> 4, lr = lane & 15;
    const int wm = wave >> 1, wn = wave & 1;
    const int bm = blockIdx.y * 128;
    const int bn = blockIdx.x * 128;

    floatx4 acc[4][4] = {};   // [mb][nb]

    auto stage = [&](int buf, int k0) {
#pragma unroll
        for (int c = 0; c < 4; ++c) {
            const int blk = c * 4 + wave;             // 0..15, wave-uniform
            const int r = blk * 8 + (lane >> 3);
            const int g = (lane & 7) ^ (r & 7);
            const __hip_bfloat16* ga = A + (size_t)(bm + r) * Dv + k0 + g * 8;
            const __hip_bfloat16* gw = Wb + (size_t)(bn + r) * Dv + k0 + g * 8;
            __builtin_amdgcn_global_load_lds(
                (const __attribute__((address_space(1))) unsigned int*)(const void*)ga,
                (__attribute__((address_space(3))) unsigned int*)(void*)&As[buf][blk * 512],
                16, 0, 0);
            __builtin_amdgcn_global_load_lds(
                (const __attribute__((address_space(1))) unsigned int*)(const void*)gw,
                (__attribute__((address_space(3))) unsigned int*)(void*)&Ws[buf][blk * 512],
                16, 0, 0);
        }
    };

    stage(0, 0);

    for (int it = 0; it < Dv / 64; ++it) {
        const int cur = it & 1;
        __syncthreads();                              // drains vmcnt: buf[cur] staged
        if (it + 1 < Dv / 64) stage(1 - cur, (it + 1) * 64);   // overlaps compute

#pragma unroll
        for (int ks = 0; ks < 2; ++ks) {
            short8 af[4];
#pragma unroll
            for (int mb = 0; mb < 4; ++mb) {
                int row = wm * 64 + mb * 16 + lr;
                af[mb] = *(const short8*)&As[cur][row * 64 + (((ks * 4 + quad) ^ (lr & 7)) << 3)];
            }
#pragma unroll
            for (int nb = 0; nb < 4; ++nb) {
                int row = wn * 64 + nb * 16 + lr;
                short8 bf = *(const short8*)&Ws[cur][row * 64 + (((ks * 4 + quad) ^ (lr & 7)) << 3)];
#pragma unroll
                for (int mb = 0; mb < 4; ++mb)
                    acc[mb][nb] = __builtin_amdgcn_mfma_f32_16x16x32_bf16(af[mb], bf, acc[mb][nb], 0, 0, 0);
            }
        }
    }

    // C/D layout: col = lane&15, row = quad*4 + reg
#pragma unroll
    for (int mb = 0; mb < 4; ++mb)
#pragma unroll
        for (int nb = 0; nb < 4; ++nb) {
            int row = bm + wm * 64 + mb * 16 + quad * 4;
            int col = bn + wn * 64 + nb * 16 + lr;
#pragma unroll
            for (int r = 0; r < 4; ++r)
                C[(size_t)(row + r) * Dv + col] = acc[mb][nb][r];
        }
}

// ---------------------------------------------------------------------------
// Stage 3: LayerNorm in place on d_out (fp32). Biased variance, eps=1e-5.
// ---------------------------------------------------------------------------
__global__ __launch_bounds__(256)
void ln_kernel(float* __restrict__ C,
               const float* __restrict__ g) {
    const int row = blockIdx.x;
    const int t = threadIdx.x;
    const int wave = t >> 6, lane = t & 63;

    float* rp = C + (size_t)row * Dv;
    float4 x = *(const float4*)(rp + t * 4);

    float s = x.x + x.y + x.z + x.w;
    float sq = x.x * x.x + x.y * x.y + x.z * x.z + x.w * x.w;
#pragma unroll
    for (int off = 32; off >= 1; off >>= 1) {
        s += __shfl_xor(s, off);
        sq += __shfl_xor(sq, off);
    }
    __shared__ float ss[4], ssq[4];
    if (lane == 0) { ss[wave] = s; ssq[wave] = sq; }
    __syncthreads();
    s = ss[0] + ss[1] + ss[2] + ss[3];
    sq = ssq[0] + ssq[1] + ssq[2] + ssq[3];

    const float rn = 1.f / (float)Dv;
    float mean = s * rn;
    float var = sq * rn - mean * mean;
    float inv = rsqrtf(var + 1e-5f);

    float4 gv = *(const float4*)(g + t * 4);

    float4 o;
    o.x = (x.x - mean) * inv * gv.x;
    o.y = (x.y - mean) * inv * gv.y;
    o.z = (x.z - mean) * inv * gv.z;
    o.w = (x.w - mean) * inv * gv.w;
    *(float4*)(rp + t * 4) = o;
}

// ---------------------------------------------------------------------------
extern "C" void kernel_launch(void* const* d_in, const int* in_sizes, int n_in,
                              void* d_out, int out_size, void* d_ws, size_t ws_size,
                              hipStream_t stream) {
    const float* q = (const float*)d_in[0];
    const float* k = (const float*)d_in[1];
    const float* v = (const float*)d_in[2];
    const float* W = (const float*)d_in[3];
    const float* g = (const float*)d_in[4];
    float* out = (float*)d_out;

    const size_t attnB = (size_t)Bv * Nv * Dv * 2;       // 16 MiB bf16 attn out
    const size_t wbB = (size_t)Dv * Dv * 2;              // 2 MiB bf16 W
    const size_t kbB = (size_t)Bv * Nv * Dv * 2;         // 16 MiB bf16 K

    __hip_bfloat16* attn = (__hip_bfloat16*)d_ws;
    __hip_bfloat16* Wb = (__hip_bfloat16*)((char*)d_ws + attnB);
    __hip_bfloat16* Kb = (__hip_bfloat16*)((char*)d_ws + attnB + wbB);
    __hip_bfloat16* Vtb = (__hip_bfloat16*)((char*)d_ws + attnB + wbB + kbB);

    prep_all<<<KCONV_BLOCKS + WCONV_BLOCKS + VT_BLOCKS, 256, 0, stream>>>(k, Kb, W, Wb, v, Vtb);
    attn_mfma_pre<<<dim3(16, 16, Bv), 256, 0, stream>>>(q, Kb, Vtb, attn);
    proj_kernel<<<dim3(Dv / 128, (Bv * Nv) / 128), 256, 0, stream>>>(attn, Wb, out);
    ln_kernel<<<Bv * Nv, 256, 0, stream>>>(out, g);
}

// Round 6
// 295.132 us; speedup vs baseline: 1.1556x; 1.0766x over previous
//
#include <hip/hip_runtime.h>
#include <hip/hip_bf16.h>

// Problem: B=4, N=2048, H=16, Dh=64, D=1024. All global tensors fp32.
// out = LN( softmax(Q K^T / 8) V @ W_out^T ) * g   (fp32 out).
// R12: attn is VALU-issue-bound (VALUBusy 70%, MfmaUtil 18%, conflicts 0).
// (1) O^T operand swap [bit-identical]: PV = mfma(V_frag, P_frag) -> C has
//     query on the lane axis -> alpha / 1/l are lane-local; removes the
//     8 alpha-bpermutes per tile + 8 linv-bpermutes at epilogue.
//     (A- and B-fragments share the [lane&15][8*quad+j] layout, so the same
//     registers serve either operand slot.)
// (2) exp via exp2(fma(s, log2e, -m*log2e)): 3->2 instr per s-value.
// (3) defer-max (T13, THR=8): skip m-update/rescale while __all(tmax<=m+8);
//     P bounded by e^8, f32 accum safe, O/l invariant.
// proj: bijective same-bm XCD grouping restored (A-panel L2 reuse).

#define Bv 4
#define Nv 2048
#define Hv 16
#define DHv 64
#define Dv 1024
#define NT (Nv / 64)

#define KCONV_BLOCKS 4096
#define WCONV_BLOCKS 512
#define VT_BLOCKS 2048

#define L2E 1.44269504088896340736f

typedef __attribute__((ext_vector_type(8))) short short8;
typedef __attribute__((ext_vector_type(4))) float floatx4;

// bf16 pair pack, round-half-up (+0x8000 then take high16 via one v_perm_b32).
__device__ inline unsigned pack_bf2(float a, float b) {
    unsigned ua = __builtin_bit_cast(unsigned, a) + 0x8000u;
    unsigned ub = __builtin_bit_cast(unsigned, b) + 0x8000u;
    return __builtin_amdgcn_perm(ub, ua, 0x07060302u);  // [b.hi16 : a.hi16]
}

// RTE bf16 pair (epilogue uses __float2bfloat16 semantics, grouped for 8B stores).
__device__ inline unsigned bf2u_rte(float a, float b) {
    unsigned short ua = __builtin_bit_cast(unsigned short, __float2bfloat16(a));
    unsigned short ub = __builtin_bit_cast(unsigned short, __float2bfloat16(b));
    return (unsigned)ua | ((unsigned)ub << 16);
}

__device__ inline void plswap16(unsigned &a, unsigned &b) {
    auto r = __builtin_amdgcn_permlane16_swap(a, b, false, false);
    a = r[0]; b = r[1];
}
__device__ inline void plswap32(unsigned &a, unsigned &b) {
    auto r = __builtin_amdgcn_permlane32_swap(a, b, false, false);
    a = r[0]; b = r[1];
}

// Cross-quad reduce via permlane self-swap: stage1 == shfl_xor 16,
// stage2 == shfl_xor 32. fmax/add commutative -> bit-identical values.
__device__ inline float redq_max(float x) {
    unsigned a = __builtin_bit_cast(unsigned, x), b = a;
    plswap16(a, b);
    float m = fmaxf(__builtin_bit_cast(float, a), __builtin_bit_cast(float, b));
    unsigned c = __builtin_bit_cast(unsigned, m), d = c;
    plswap32(c, d);
    return fmaxf(__builtin_bit_cast(float, c), __builtin_bit_cast(float, d));
}
__device__ inline float redq_sum(float x) {
    unsigned a = __builtin_bit_cast(unsigned, x), b = a;
    plswap16(a, b);
    float m = __builtin_bit_cast(float, a) + __builtin_bit_cast(float, b);
    unsigned c = __builtin_bit_cast(unsigned, m), d = c;
    plswap32(c, d);
    return __builtin_bit_cast(float, c) + __builtin_bit_cast(float, d);
}

// ---------------------------------------------------------------------------
// Fused prep (one launch): K f32->bf16 (4096 blk), W f32->bf16 (512 blk),
// V f32 -> V^T bf16 [b][h][64][2048] (2048 blk). pack_bf2 rounding keeps all
// downstream operand bits identical.
// ---------------------------------------------------------------------------
__global__ __launch_bounds__(256)
void prep_all(const float* __restrict__ K, __hip_bfloat16* __restrict__ Kb,
              const float* __restrict__ W, __hip_bfloat16* __restrict__ Wb,
              const float* __restrict__ v, __hip_bfloat16* __restrict__ vt) {
    __shared__ short T[64][72];   // vtrans scratch (+8 pad)
    int bid = blockIdx.x;
    if (bid < KCONV_BLOCKS + WCONV_BLOCKS) {
        const float* src;
        __hip_bfloat16* dst;
        if (bid < KCONV_BLOCKS) { src = K; dst = Kb; }
        else { src = W; dst = Wb; bid -= KCONV_BLOCKS; }
        int base = (bid * 256 + threadIdx.x) * 8;
        float4 f0 = *(const float4*)(src + base);
        float4 f1 = *(const float4*)(src + base + 4);
        uint4 u;
        u.x = pack_bf2(f0.x, f0.y);
        u.y = pack_bf2(f0.z, f0.w);
        u.z = pack_bf2(f1.x, f1.y);
        u.w = pack_bf2(f1.z, f1.w);
        *(uint4*)(dst + base) = u;
        return;
    }
    bid -= KCONV_BLOCKS + WCONV_BLOCKS;        // 0..2047
    const int b = bid >> 9;                    // 512 per batch
    const int rem = bid & 511;
    const int h = rem >> 5;                    // 16 heads
    const int n0 = (rem & 31) * 64;            // 32 n-tiles
    const int t = threadIdx.x;
    const int ir = t >> 4;
    const int d4 = (t & 15) * 4;
#pragma unroll
    for (int pass = 0; pass < 4; ++pass) {
        int n = pass * 16 + ir;
        float4 f = *(const float4*)(v + ((size_t)b * Nv + n0 + n) * Dv + h * DHv + d4);
        T[d4 + 0][n] = (short)(pack_bf2(f.x, f.x) & 0xffffu);
        T[d4 + 1][n] = (short)(pack_bf2(f.y, f.y) & 0xffffu);
        T[d4 + 2][n] = (short)(pack_bf2(f.z, f.z) & 0xffffu);
        T[d4 + 3][n] = (short)(pack_bf2(f.w, f.w) & 0xffffu);
    }
    __syncthreads();
    const int d = t >> 2, kg = (t & 3) * 16;
    unsigned u[8];
#pragma unroll
    for (int i = 0; i < 8; ++i)
        u[i] = (unsigned)(unsigned short)T[d][kg + 2 * i] |
               ((unsigned)(unsigned short)T[d][kg + 2 * i + 1] << 16);
    __hip_bfloat16* op = vt + ((size_t)(b * Hv + h) * DHv + d) * Nv + n0 + kg;
    *(uint4*)op = *(uint4*)&u[0];
    *(uint4*)(op + 8) = *(uint4*)&u[4];
}

// ---------------------------------------------------------------------------
// MFMA flash attention, prep-fed, O^T accumulation. Block = 256 thr (4 waves)
// = 128 queries of one (b,h). Q frags in registers. K / V^T staged via
// global_load_lds w16 (source-side inverse XOR swizzle, LDS linear).
// Softmax cross-lane via permlane; alpha/linv lane-local (O^T).
// ---------------------------------------------------------------------------
__global__ __launch_bounds__(256)
void attn_mfma_pre(const float* __restrict__ q,
                   const __hip_bfloat16* __restrict__ Kb,
                   const __hip_bfloat16* __restrict__ Vtb,
                   __hip_bfloat16* __restrict__ out) {
    __shared__ __align__(16) short Kt[2][64 * 64];   // 16 KB
    __shared__ __align__(16) short Vt[2][64 * 64];   // 16 KB (V^T: rows = d)

    const int t = threadIdx.x;
    const int wave = t >> 6, lane = t & 63;
    const int quad = lane >> 4, lr = lane & 15;
    const int b = blockIdx.z;
    // bijective XCD swizzle over (qtile,head): same-h blocks -> same XCD.
    const int lid2 = blockIdx.y * 16 + blockIdx.x;   // 0..255
    const int xcd = lid2 & 7, jj = lid2 >> 3;        // jj 0..31
    const int h = xcd * 2 + (jj >> 4);
    const int q0 = (jj & 15) * 128;
    const size_t qbh = ((size_t)b * Nv) * Dv + h * DHv;
    const __hip_bfloat16* kb = Kb + (size_t)b * Nv * Dv + h * DHv;
    const __hip_bfloat16* vtb = Vtb + (size_t)(b * Hv + h) * DHv * Nv;

    const int srow = lane >> 3;   // row within 8-row chunk
    const int sg = lane & 7;      // stored group
    auto stage = [&](int buf, int k0) {
#pragma unroll
        for (int c = 0; c < 2; ++c) {
            int blk = wave * 2 + c;          // 0..7, wave-uniform
            int r = blk * 8 + srow;
            int g = sg ^ (r & 7);            // inverse swizzle on source
            __builtin_amdgcn_global_load_lds(
                (const __attribute__((address_space(1))) unsigned*)(const void*)
                    (kb + (size_t)(k0 + r) * Dv + g * 8),
                (__attribute__((address_space(3))) unsigned*)(void*)&Kt[buf][blk * 512],
                16, 0, 0);
            __builtin_amdgcn_global_load_lds(
                (const __attribute__((address_space(1))) unsigned*)(const void*)
                    (vtb + (size_t)r * Nv + k0 + g * 8),
                (__attribute__((address_space(3))) unsigned*)(void*)&Vt[buf][blk * 512],
                16, 0, 0);
        }
    };

    stage(0, 0);   // K/V tile-0 DMA in flight first

    // ---- Q fragments direct from global (once), scale 0.125 exact ----
    short8 qfrag[2][2];   // [qs][kh]: Q[q = q0+w*32+qs*16+lr][d = 32kh+8quad+j]
#pragma unroll
    for (int qs = 0; qs < 2; ++qs)
#pragma unroll
        for (int kh = 0; kh < 2; ++kh) {
            int row = q0 + wave * 32 + qs * 16 + lr;
            const float* qp = q + qbh + (size_t)row * Dv + kh * 32 + quad * 8;
            float4 f0 = *(const float4*)qp;
            float4 f1 = *(const float4*)(qp + 4);
            int4 qi;
            qi.x = (int)pack_bf2(f0.x * 0.125f, f0.y * 0.125f);
            qi.y = (int)pack_bf2(f0.z * 0.125f, f0.w * 0.125f);
            qi.z = (int)pack_bf2(f1.x * 0.125f, f1.y * 0.125f);
            qi.w = (int)pack_bf2(f1.z * 0.125f, f1.w * 0.125f);
            qfrag[qs][kh] = __builtin_bit_cast(short8, qi);
        }

    floatx4 o_acc[2][4] = {};        // O^T: [qs][td]: O[q=lr][d=16td+4quad+r]
    float mrow[2] = {-INFINITY, -INFINITY};   // per-query (lane-local, lr)
    float lrow[2] = {0.f, 0.f};

    for (int it = 0; it < NT; ++it) {
        const int cur = it & 1;
        __syncthreads();                         // vmcnt drained: buf[cur] staged
        if (it + 1 < NT) stage(1 - cur, (it + 1) * 64);   // latency hidden by compute

        // ---- S^T = K·Q^T ----
        floatx4 s_acc[2][4] = {};
#pragma unroll
        for (int tt = 0; tt < 4; ++tt) {
            int row = tt * 16 + lr;
            short8 kf0 = *(const short8*)&Kt[cur][row * 64 + ((quad ^ (lr & 7)) << 3)];
            short8 kf1 = *(const short8*)&Kt[cur][row * 64 + (((4 + quad) ^ (lr & 7)) << 3)];
#pragma unroll
            for (int qs = 0; qs < 2; ++qs) {
                s_acc[qs][tt] = __builtin_amdgcn_mfma_f32_16x16x32_bf16(kf0, qfrag[qs][0], s_acc[qs][tt], 0, 0, 0);
                s_acc[qs][tt] = __builtin_amdgcn_mfma_f32_16x16x32_bf16(kf1, qfrag[qs][1], s_acc[qs][tt], 0, 0, 0);
            }
        }

        // ---- online softmax (defer-max) + P pack ----
        unsigned p2[2][8];
#pragma unroll
        for (int qs = 0; qs < 2; ++qs) {
            float t4[4];
#pragma unroll
            for (int tt = 0; tt < 4; ++tt)
                t4[tt] = fmaxf(fmaxf(s_acc[qs][tt][0], s_acc[qs][tt][1]),
                               fmaxf(s_acc[qs][tt][2], s_acc[qs][tt][3]));
            float tmax = fmaxf(fmaxf(t4[0], t4[1]), fmaxf(t4[2], t4[3]));
            tmax = redq_max(tmax);
            // defer-max: only rescale when some query's max grew past THR=8.
            if (!__all(tmax <= mrow[qs] + 8.0f)) {
                float mnew = fmaxf(mrow[qs], tmax);
                float alpha = __expf(mrow[qs] - mnew);   // first tile: exp(-inf)=0
                mrow[qs] = mnew;
                lrow[qs] *= alpha;
#pragma unroll
                for (int td = 0; td < 4; ++td)
#pragma unroll
                    for (int r2 = 0; r2 < 4; ++r2) o_acc[qs][td][r2] *= alpha;  // lane-local!
            }
            float mc = mrow[qs] * L2E;
            float psum = 0.f;
#pragma unroll
            for (int tt = 0; tt < 4; ++tt)
#pragma unroll
                for (int r2 = 0; r2 < 4; ++r2) {
                    float p = __builtin_amdgcn_exp2f(__builtin_fmaf(s_acc[qs][tt][r2], L2E, -mc));
                    s_acc[qs][tt][r2] = p;
                    psum += p;
                }
            psum = redq_sum(psum);
            lrow[qs] += psum;
#pragma unroll
            for (int tt = 0; tt < 4; ++tt) {
                p2[qs][tt * 2 + 0] = pack_bf2(s_acc[qs][tt][0], s_acc[qs][tt][1]);
                p2[qs][tt * 2 + 1] = pack_bf2(s_acc[qs][tt][2], s_acc[qs][tt][3]);
            }
        }

        // ---- PV as O^T += V^T·P^T: mfma(V_frag, P_frag) — operand swap.
        // P-gather per pair (x,y): swap32 -> a=[x.lo,y.lo] b=[x.hi,y.hi];
        // swap16 -> a=[x0,x2,y0,y2] b=[x1,x3,y1,y3]. Same registers serve
        // the B-operand slot (A/B frags share [lane&15][8*quad+j] layout). ----
#pragma unroll
        for (int kh = 0; kh < 2; ++kh) {
            short8 af[2];
#pragma unroll
            for (int qs = 0; qs < 2; ++qs) {
                int tlo = 4 * kh, thi = 4 * kh + 2;
                unsigned a0 = p2[qs][tlo + 0], b0 = p2[qs][thi + 0];
                unsigned a1 = p2[qs][tlo + 1], b1 = p2[qs][thi + 1];
                plswap32(a0, b0);
                plswap16(a0, b0);
                plswap32(a1, b1);
                plswap16(a1, b1);
                int4 afi;
                afi.x = (int)a0;
                afi.y = (int)a1;
                afi.z = (int)b0;
                afi.w = (int)b1;
                af[qs] = __builtin_bit_cast(short8, afi);
            }
#pragma unroll
            for (int td = 0; td < 4; ++td) {
                int d = td * 16 + lr;
                short8 vf = *(const short8*)&Vt[cur][d * 64 + (((kh * 4 + quad) ^ (lr & 7)) << 3)];
                o_acc[0][td] = __builtin_amdgcn_mfma_f32_16x16x32_bf16(vf, af[0], o_acc[0][td], 0, 0, 0);
                o_acc[1][td] = __builtin_amdgcn_mfma_f32_16x16x32_bf16(vf, af[1], o_acc[1][td], 0, 0, 0);
            }
        }
    }

    // ---- epilogue (O^T): lane owns query q = q0+wave*32+qs*16+lr;
    // d = td*16 + quad*4 + r2 -> 8B grouped stores. linv lane-local. ----
#pragma unroll
    for (int qs = 0; qs < 2; ++qs) {
        float linv = 1.f / lrow[qs];
        int qrow = q0 + wave * 32 + qs * 16 + lr;
        __hip_bfloat16* op = out + ((size_t)(b * Nv + qrow)) * Dv + h * DHv + quad * 4;
#pragma unroll
        for (int td = 0; td < 4; ++td) {
            uint2 w;
            w.x = bf2u_rte(o_acc[qs][td][0] * linv, o_acc[qs][td][1] * linv);
            w.y = bf2u_rte(o_acc[qs][td][2] * linv, o_acc[qs][td][3] * linv);
            *(uint2*)(op + td * 16) = w;
        }
    }
}

// ---------------------------------------------------------------------------
// Stage 2: C = A @ Wb^T. m97-structure: 128x128 tile, BK=64, double-buffered
// LDS, global_load_lds w16, XOR-swizzled (row&7) 128B rows. Bijective XCD
// grouping: the 8 bn-blocks sharing an A-panel (same bm) land on one XCD.
// ---------------------------------------------------------------------------
__global__ __launch_bounds__(256)
void proj_kernel(const __hip_bfloat16* __restrict__ A,
                 const __hip_bfloat16* __restrict__ Wb,
                 float* __restrict__ C) {
    __shared__ __align__(16) short As[2][128 * 64];  // 32 KB
    __shared__ __align__(16) short Ws[2][128 * 64];  // 32 KB

    const int t = threadIdx.x;
    const int wave = t >> 6, lane = t & 63;
    const int quad = lane >> 4, lr = lane & 15;
    const int wm = wave >> 1, wn = wave & 1;
    // XCD grouping: phys bx round-robins XCDs; give each XCD 8 consecutive
    // bm-panels, all 8 bn per bm on the same XCD.
    const int bx = blockIdx.x;                 // 0..511
    const int xcd = bx & 7, j = bx >> 3;       // j 0..63
    const int bm = (xcd * 8 + (j >> 3)) * 128;
    const int bn = (j & 7) * 128;

    floatx4 acc[4][4] = {};   // [mb][nb]

    auto stage = [&](int buf, int k0) {
#pragma unroll
        for (int c = 0; c < 4; ++c) {
            const int blk = c * 4 + wave;             // 0..15, wave-uniform
            const int r = blk * 8 + (lane >> 3);
            const int g = (lane & 7) ^ (r & 7);
            const __hip_bfloat16* ga = A + (size_t)(bm + r) * Dv + k0 + g * 8;
            const __hip_bfloat16* gw = Wb + (size_t)(bn + r) * Dv + k0 + g * 8;
            __builtin_amdgcn_global_load_lds(
                (const __attribute__((address_space(1))) unsigned int*)(const void*)ga,
                (__attribute__((address_space(3))) unsigned int*)(void*)&As[buf][blk * 512],
                16, 0, 0);
            __builtin_amdgcn_global_load_lds(
                (const __attribute__((address_space(1))) unsigned int*)(const void*)gw,
                (__attribute__((address_space(3))) unsigned int*)(void*)&Ws[buf][blk * 512],
                16, 0, 0);
        }
    };

    stage(0, 0);

    for (int it = 0; it < Dv / 64; ++it) {
        const int cur = it & 1;
        __syncthreads();                              // drains vmcnt: buf[cur] staged
        if (it + 1 < Dv / 64) stage(1 - cur, (it + 1) * 64);   // overlaps compute

#pragma unroll
        for (int ks = 0; ks < 2; ++ks) {
            short8 af[4];
#pragma unroll
            for (int mb = 0; mb < 4; ++mb) {
                int row = wm * 64 + mb * 16 + lr;
                af[mb] = *(const short8*)&As[cur][row * 64 + (((ks * 4 + quad) ^ (lr & 7)) << 3)];
            }
#pragma unroll
            for (int nb = 0; nb < 4; ++nb) {
                int row = wn * 64 + nb * 16 + lr;
                short8 bf = *(const short8*)&Ws[cur][row * 64 + (((ks * 4 + quad) ^ (lr & 7)) << 3)];
#pragma unroll
                for (int mb = 0; mb < 4; ++mb)
                    acc[mb][nb] = __builtin_amdgcn_mfma_f32_16x16x32_bf16(af[mb], bf, acc[mb][nb], 0, 0, 0);
            }
        }
    }

    // C/D layout: col = lane&15, row = quad*4 + reg
#pragma unroll
    for (int mb = 0; mb < 4; ++mb)
#pragma unroll
        for (int nb = 0; nb < 4; ++nb) {
            int row = bm + wm * 64 + mb * 16 + quad * 4;
            int col = bn + wn * 64 + nb * 16 + lr;
#pragma unroll
            for (int r = 0; r < 4; ++r)
                C[(size_t)(row + r) * Dv + col] = acc[mb][nb][r];
        }
}

// ---------------------------------------------------------------------------
// Stage 3: LayerNorm in place on d_out (fp32). Biased variance, eps=1e-5.
// ---------------------------------------------------------------------------
__global__ __launch_bounds__(256)
void ln_kernel(float* __restrict__ C,
               const float* __restrict__ g) {
    const int row = blockIdx.x;
    const int t = threadIdx.x;
    const int wave = t >> 6, lane = t & 63;

    float* rp = C + (size_t)row * Dv;
    float4 x = *(const float4*)(rp + t * 4);

    float s = x.x + x.y + x.z + x.w;
    float sq = x.x * x.x + x.y * x.y + x.z * x.z + x.w * x.w;
#pragma unroll
    for (int off = 32; off >= 1; off >>= 1) {
        s += __shfl_xor(s, off);
        sq += __shfl_xor(sq, off);
    }
    __shared__ float ss[4], ssq[4];
    if (lane == 0) { ss[wave] = s; ssq[wave] = sq; }
    __syncthreads();
    s = ss[0] + ss[1] + ss[2] + ss[3];
    sq = ssq[0] + ssq[1] + ssq[2] + ssq[3];

    const float rn = 1.f / (float)Dv;
    float mean = s * rn;
    float var = sq * rn - mean * mean;
    float inv = rsqrtf(var + 1e-5f);

    float4 gv = *(const float4*)(g + t * 4);

    float4 o;
    o.x = (x.x - mean) * inv * gv.x;
    o.y = (x.y - mean) * inv * gv.y;
    o.z = (x.z - mean) * inv * gv.z;
    o.w = (x.w - mean) * inv * gv.w;
    *(float4*)(rp + t * 4) = o;
}

// ---------------------------------------------------------------------------
extern "C" void kernel_launch(void* const* d_in, const int* in_sizes, int n_in,
                              void* d_out, int out_size, void* d_ws, size_t ws_size,
                              hipStream_t stream) {
    const float* q = (const float*)d_in[0];
    const float* k = (const float*)d_in[1];
    const float* v = (const float*)d_in[2];
    const float* W = (const float*)d_in[3];
    const float* g = (const float*)d_in[4];
    float* out = (float*)d_out;

    const size_t attnB = (size_t)Bv * Nv * Dv * 2;       // 16 MiB bf16 attn out
    const size_t wbB = (size_t)Dv * Dv * 2;              // 2 MiB bf16 W
    const size_t kbB = (size_t)Bv * Nv * Dv * 2;         // 16 MiB bf16 K

    __hip_bfloat16* attn = (__hip_bfloat16*)d_ws;
    __hip_bfloat16* Wb = (__hip_bfloat16*)((char*)d_ws + attnB);
    __hip_bfloat16* Kb = (__hip_bfloat16*)((char*)d_ws + attnB + wbB);
    __hip_bfloat16* Vtb = (__hip_bfloat16*)((char*)d_ws + attnB + wbB + kbB);

    prep_all<<<KCONV_BLOCKS + WCONV_BLOCKS + VT_BLOCKS, 256, 0, stream>>>(k, Kb, W, Wb, v, Vtb);
    attn_mfma_pre<<<dim3(16, 16, Bv), 256, 0, stream>>>(q, Kb, Vtb, attn);
    proj_kernel<<<512, 256, 0, stream>>>(attn, Wb, out);
    ln_kernel<<<Bv * Nv, 256, 0, stream>>>(out, g);
}

// Round 8
// 289.744 us; speedup vs baseline: 1.1771x; 1.0186x over previous
//
#include <hip/hip_runtime.h>
#include <hip/hip_bf16.h>

// Problem: B=4, N=2048, H=16, Dh=64, D=1024. All global tensors fp32.
// out = LN( softmax(Q K^T / 8) V @ W_out^T ) * g   (fp32 out).
// R14 = R13 with the invalid v_pk_max_f32 removed (gfx950 has NO packed
// f32 max; only v_pk_{fma,mul,add}_f32). Max tree is scalar fmax triples
// (clang fuses to v_max3_f32). Kept from R13:
//  (1) #pragma unroll 2 on the key-tile loop -> LDS addrs loop-invariant.
//  (2) v_pk_fma_f32 for the exp2 argument (valid, per-lane identical).
//  (3) prep vtrans LDS pad 72->76.
// proj/ln/prep-structure unchanged from R12 (verified at 295us total).

#define Bv 4
#define Nv 2048
#define Hv 16
#define DHv 64
#define Dv 1024
#define NT (Nv / 64)

#define KCONV_BLOCKS 4096
#define WCONV_BLOCKS 512
#define VT_BLOCKS 2048

#define L2E 1.44269504088896340736f

typedef __attribute__((ext_vector_type(8))) short short8;
typedef __attribute__((ext_vector_type(4))) float floatx4;
typedef __attribute__((ext_vector_type(2))) float float2v;

#define LOPAIR(v) __builtin_shufflevector(v, v, 0, 1)
#define HIPAIR(v) __builtin_shufflevector(v, v, 2, 3)

// bf16 pair pack, round-half-up (+0x8000 then take high16 via one v_perm_b32).
__device__ inline unsigned pack_bf2(float a, float b) {
    unsigned ua = __builtin_bit_cast(unsigned, a) + 0x8000u;
    unsigned ub = __builtin_bit_cast(unsigned, b) + 0x8000u;
    return __builtin_amdgcn_perm(ub, ua, 0x07060302u);  // [b.hi16 : a.hi16]
}

// RTE bf16 pair (epilogue, grouped for 8B stores).
__device__ inline unsigned bf2u_rte(float a, float b) {
    unsigned short ua = __builtin_bit_cast(unsigned short, __float2bfloat16(a));
    unsigned short ub = __builtin_bit_cast(unsigned short, __float2bfloat16(b));
    return (unsigned)ua | ((unsigned)ub << 16);
}

// Packed f32 fma (valid on gfx950). Per-component identical to scalar fma.
__device__ inline float2v pk_fma(float2v a, float2v b, float2v c) {
    float2v d;
    asm("v_pk_fma_f32 %0, %1, %2, %3" : "=v"(d) : "v"(a), "v"(b), "v"(c));
    return d;
}

// 3-input max; clang fuses nested fmaxf to v_max3_f32 on gfx9+.
__device__ inline float max3f(float a, float b, float c) {
    return fmaxf(fmaxf(a, b), c);
}

__device__ inline void plswap16(unsigned &a, unsigned &b) {
    auto r = __builtin_amdgcn_permlane16_swap(a, b, false, false);
    a = r[0]; b = r[1];
}
__device__ inline void plswap32(unsigned &a, unsigned &b) {
    auto r = __builtin_amdgcn_permlane32_swap(a, b, false, false);
    a = r[0]; b = r[1];
}

// Cross-quad reduce via permlane self-swap (== shfl_xor 16 then 32).
__device__ inline float redq_max(float x) {
    unsigned a = __builtin_bit_cast(unsigned, x), b = a;
    plswap16(a, b);
    float m = fmaxf(__builtin_bit_cast(float, a), __builtin_bit_cast(float, b));
    unsigned c = __builtin_bit_cast(unsigned, m), d = c;
    plswap32(c, d);
    return fmaxf(__builtin_bit_cast(float, c), __builtin_bit_cast(float, d));
}
__device__ inline float redq_sum(float x) {
    unsigned a = __builtin_bit_cast(unsigned, x), b = a;
    plswap16(a, b);
    float m = __builtin_bit_cast(float, a) + __builtin_bit_cast(float, b);
    unsigned c = __builtin_bit_cast(unsigned, m), d = c;
    plswap32(c, d);
    return __builtin_bit_cast(float, c) + __builtin_bit_cast(float, d);
}

// ---------------------------------------------------------------------------
// Fused prep (one launch): K f32->bf16 (4096 blk), W f32->bf16 (512 blk),
// V f32 -> V^T bf16 [b][h][64][2048] (2048 blk). pack_bf2 rounding keeps all
// downstream operand bits identical.
// ---------------------------------------------------------------------------
__global__ __launch_bounds__(256)
void prep_all(const float* __restrict__ K, __hip_bfloat16* __restrict__ Kb,
              const float* __restrict__ W, __hip_bfloat16* __restrict__ Wb,
              const float* __restrict__ v, __hip_bfloat16* __restrict__ vt) {
    __shared__ short T[64][76];   // vtrans scratch (+12 pad: 4-way wr, ~free rd)
    int bid = blockIdx.x;
    if (bid < KCONV_BLOCKS + WCONV_BLOCKS) {
        const float* src;
        __hip_bfloat16* dst;
        if (bid < KCONV_BLOCKS) { src = K; dst = Kb; }
        else { src = W; dst = Wb; bid -= KCONV_BLOCKS; }
        int base = (bid * 256 + threadIdx.x) * 8;
        float4 f0 = *(const float4*)(src + base);
        float4 f1 = *(const float4*)(src + base + 4);
        uint4 u;
        u.x = pack_bf2(f0.x, f0.y);
        u.y = pack_bf2(f0.z, f0.w);
        u.z = pack_bf2(f1.x, f1.y);
        u.w = pack_bf2(f1.z, f1.w);
        *(uint4*)(dst + base) = u;
        return;
    }
    bid -= KCONV_BLOCKS + WCONV_BLOCKS;        // 0..2047
    const int b = bid >> 9;                    // 512 per batch
    const int rem = bid & 511;
    const int h = rem >> 5;                    // 16 heads
    const int n0 = (rem & 31) * 64;            // 32 n-tiles
    const int t = threadIdx.x;
    const int ir = t >> 4;
    const int d4 = (t & 15) * 4;
#pragma unroll
    for (int pass = 0; pass < 4; ++pass) {
        int n = pass * 16 + ir;
        float4 f = *(const float4*)(v + ((size_t)b * Nv + n0 + n) * Dv + h * DHv + d4);
        T[d4 + 0][n] = (short)(pack_bf2(f.x, f.x) & 0xffffu);
        T[d4 + 1][n] = (short)(pack_bf2(f.y, f.y) & 0xffffu);
        T[d4 + 2][n] = (short)(pack_bf2(f.z, f.z) & 0xffffu);
        T[d4 + 3][n] = (short)(pack_bf2(f.w, f.w) & 0xffffu);
    }
    __syncthreads();
    const int d = t >> 2, kg = (t & 3) * 16;
    unsigned u[8];
#pragma unroll
    for (int i = 0; i < 8; ++i)
        u[i] = (unsigned)(unsigned short)T[d][kg + 2 * i] |
               ((unsigned)(unsigned short)T[d][kg + 2 * i + 1] << 16);
    __hip_bfloat16* op = vt + ((size_t)(b * Hv + h) * DHv + d) * Nv + n0 + kg;
    *(uint4*)op = *(uint4*)&u[0];
    *(uint4*)(op + 8) = *(uint4*)&u[4];
}

// ---------------------------------------------------------------------------
// MFMA flash attention, prep-fed, O^T accumulation. Block = 256 thr (4 waves)
// = 128 queries of one (b,h). Q frags in registers. K / V^T staged via
// global_load_lds w16 (source-side inverse XOR swizzle, LDS linear).
// Softmax cross-lane via permlane; alpha/linv lane-local (O^T).
// Main loop unrolled x2 so the LDS buffer index is compile-time.
// ---------------------------------------------------------------------------
__global__ __launch_bounds__(256)
void attn_mfma_pre(const float* __restrict__ q,
                   const __hip_bfloat16* __restrict__ Kb,
                   const __hip_bfloat16* __restrict__ Vtb,
                   __hip_bfloat16* __restrict__ out) {
    __shared__ __align__(16) short Kt[2][64 * 64];   // 16 KB
    __shared__ __align__(16) short Vt[2][64 * 64];   // 16 KB (V^T: rows = d)

    const int t = threadIdx.x;
    const int wave = t >> 6, lane = t & 63;
    const int quad = lane >> 4, lr = lane & 15;
    const int b = blockIdx.z;
    // bijective XCD swizzle over (qtile,head): same-h blocks -> same XCD.
    const int lid2 = blockIdx.y * 16 + blockIdx.x;   // 0..255
    const int xcd = lid2 & 7, jj = lid2 >> 3;        // jj 0..31
    const int h = xcd * 2 + (jj >> 4);
    const int q0 = (jj & 15) * 128;
    const size_t qbh = ((size_t)b * Nv) * Dv + h * DHv;
    const __hip_bfloat16* kb = Kb + (size_t)b * Nv * Dv + h * DHv;
    const __hip_bfloat16* vtb = Vtb + (size_t)(b * Hv + h) * DHv * Nv;

    const int srow = lane >> 3;   // row within 8-row chunk
    const int sg = lane & 7;      // stored group
    auto stage = [&](int buf, int k0) {
#pragma unroll
        for (int c = 0; c < 2; ++c) {
            int blk = wave * 2 + c;          // 0..7, wave-uniform
            int r = blk * 8 + srow;
            int g = sg ^ (r & 7);            // inverse swizzle on source
            __builtin_amdgcn_global_load_lds(
                (const __attribute__((address_space(1))) unsigned*)(const void*)
                    (kb + (size_t)(k0 + r) * Dv + g * 8),
                (__attribute__((address_space(3))) unsigned*)(void*)&Kt[buf][blk * 512],
                16, 0, 0);
            __builtin_amdgcn_global_load_lds(
                (const __attribute__((address_space(1))) unsigned*)(const void*)
                    (vtb + (size_t)r * Nv + k0 + g * 8),
                (__attribute__((address_space(3))) unsigned*)(void*)&Vt[buf][blk * 512],
                16, 0, 0);
        }
    };

    stage(0, 0);   // K/V tile-0 DMA in flight first

    // ---- Q fragments direct from global (once), scale 0.125 exact ----
    short8 qfrag[2][2];   // [qs][kh]: Q[q = q0+w*32+qs*16+lr][d = 32kh+8quad+j]
#pragma unroll
    for (int qs = 0; qs < 2; ++qs)
#pragma unroll
        for (int kh = 0; kh < 2; ++kh) {
            int row = q0 + wave * 32 + qs * 16 + lr;
            const float* qp = q + qbh + (size_t)row * Dv + kh * 32 + quad * 8;
            float4 f0 = *(const float4*)qp;
            float4 f1 = *(const float4*)(qp + 4);
            int4 qi;
            qi.x = (int)pack_bf2(f0.x * 0.125f, f0.y * 0.125f);
            qi.y = (int)pack_bf2(f0.z * 0.125f, f0.w * 0.125f);
            qi.z = (int)pack_bf2(f1.x * 0.125f, f1.y * 0.125f);
            qi.w = (int)pack_bf2(f1.z * 0.125f, f1.w * 0.125f);
            qfrag[qs][kh] = __builtin_bit_cast(short8, qi);
        }

    floatx4 o_acc[2][4] = {};        // O^T: [qs][td]: O[q=lr][d=16td+4quad+r]
    float mrow[2] = {-INFINITY, -INFINITY};   // per-query (lane-local, lr)
    float lrow[2] = {0.f, 0.f};
    const float2v l2e2 = {L2E, L2E};

#pragma unroll 2
    for (int it = 0; it < NT; ++it) {
        const int cur = it & 1;                  // compile-time under unroll 2
        __syncthreads();                         // vmcnt drained: buf[cur] staged
        if (it + 1 < NT) stage(1 - cur, (it + 1) * 64);   // latency hidden by compute

        // ---- S^T = K·Q^T ----
        floatx4 s_acc[2][4] = {};
#pragma unroll
        for (int tt = 0; tt < 4; ++tt) {
            int row = tt * 16 + lr;
            short8 kf0 = *(const short8*)&Kt[cur][row * 64 + ((quad ^ (lr & 7)) << 3)];
            short8 kf1 = *(const short8*)&Kt[cur][row * 64 + (((4 + quad) ^ (lr & 7)) << 3)];
#pragma unroll
            for (int qs = 0; qs < 2; ++qs) {
                s_acc[qs][tt] = __builtin_amdgcn_mfma_f32_16x16x32_bf16(kf0, qfrag[qs][0], s_acc[qs][tt], 0, 0, 0);
                s_acc[qs][tt] = __builtin_amdgcn_mfma_f32_16x16x32_bf16(kf1, qfrag[qs][1], s_acc[qs][tt], 0, 0, 0);
            }
        }

        // ---- online softmax (defer-max) + P pack ----
        unsigned p2[2][8];
#pragma unroll
        for (int qs = 0; qs < 2; ++qs) {
            // 16-value max via max3 triples (6 ops; commutative reorder only).
            float m0 = max3f(s_acc[qs][0][0], s_acc[qs][0][1], s_acc[qs][0][2]);
            float m1 = max3f(s_acc[qs][0][3], s_acc[qs][1][0], s_acc[qs][1][1]);
            float m2 = max3f(s_acc[qs][1][2], s_acc[qs][1][3], s_acc[qs][2][0]);
            float m3 = max3f(s_acc[qs][2][1], s_acc[qs][2][2], s_acc[qs][2][3]);
            float m4 = max3f(s_acc[qs][3][0], s_acc[qs][3][1], s_acc[qs][3][2]);
            float m5 = max3f(m0, m1, s_acc[qs][3][3]);
            float tmax = redq_max(max3f(m5, max3f(m2, m3, m4), -INFINITY));
            // defer-max: only rescale when some query's max grew past THR=8.
            if (!__all(tmax <= mrow[qs] + 8.0f)) {
                float mnew = fmaxf(mrow[qs], tmax);
                float alpha = __expf(mrow[qs] - mnew);   // first tile: exp(-inf)=0
                mrow[qs] = mnew;
                lrow[qs] *= alpha;
#pragma unroll
                for (int td = 0; td < 4; ++td)
#pragma unroll
                    for (int r2 = 0; r2 < 4; ++r2) o_acc[qs][td][r2] *= alpha;  // lane-local
            }
            float negmc = -(mrow[qs] * L2E);
            float2v mcn2 = {negmc, negmc};
            float psum = 0.f;
#pragma unroll
            for (int tt = 0; tt < 4; ++tt) {
                float2v e0 = pk_fma(LOPAIR(s_acc[qs][tt]), l2e2, mcn2);
                float2v e1 = pk_fma(HIPAIR(s_acc[qs][tt]), l2e2, mcn2);
                float p0 = __builtin_amdgcn_exp2f(e0.x);
                float p1 = __builtin_amdgcn_exp2f(e0.y);
                float p2v_ = __builtin_amdgcn_exp2f(e1.x);
                float p3 = __builtin_amdgcn_exp2f(e1.y);
                psum += (p0 + p1) + (p2v_ + p3);
                p2[qs][tt * 2 + 0] = pack_bf2(p0, p1);
                p2[qs][tt * 2 + 1] = pack_bf2(p2v_, p3);
            }
            lrow[qs] += redq_sum(psum);
        }

        // ---- PV as O^T += V^T·P^T: mfma(V_frag, P_frag). P-gather per pair
        // (x,y): swap32 -> a=[x.lo,y.lo] b=[x.hi,y.hi]; swap16 ->
        // a=[x0,x2,y0,y2] b=[x1,x3,y1,y3] == srcA/srcB words. ----
#pragma unroll
        for (int kh = 0; kh < 2; ++kh) {
            short8 af[2];
#pragma unroll
            for (int qs = 0; qs < 2; ++qs) {
                int tlo = 4 * kh, thi = 4 * kh + 2;
                unsigned a0 = p2[qs][tlo + 0], b0 = p2[qs][thi + 0];
                unsigned a1 = p2[qs][tlo + 1], b1 = p2[qs][thi + 1];
                plswap32(a0, b0);
                plswap16(a0, b0);
                plswap32(a1, b1);
                plswap16(a1, b1);
                int4 afi;
                afi.x = (int)a0;
                afi.y = (int)a1;
                afi.z = (int)b0;
                afi.w = (int)b1;
                af[qs] = __builtin_bit_cast(short8, afi);
            }
#pragma unroll
            for (int td = 0; td < 4; ++td) {
                int d = td * 16 + lr;
                short8 vf = *(const short8*)&Vt[cur][d * 64 + (((kh * 4 + quad) ^ (lr & 7)) << 3)];
                o_acc[0][td] = __builtin_amdgcn_mfma_f32_16x16x32_bf16(vf, af[0], o_acc[0][td], 0, 0, 0);
                o_acc[1][td] = __builtin_amdgcn_mfma_f32_16x16x32_bf16(vf, af[1], o_acc[1][td], 0, 0, 0);
            }
        }
    }

    // ---- epilogue (O^T): lane owns query q = q0+wave*32+qs*16+lr;
    // d = td*16 + quad*4 + r2 -> 8B grouped stores. linv lane-local. ----
#pragma unroll
    for (int qs = 0; qs < 2; ++qs) {
        float linv = 1.f / lrow[qs];
        int qrow = q0 + wave * 32 + qs * 16 + lr;
        __hip_bfloat16* op = out + ((size_t)(b * Nv + qrow)) * Dv + h * DHv + quad * 4;
#pragma unroll
        for (int td = 0; td < 4; ++td) {
            uint2 w;
            w.x = bf2u_rte(o_acc[qs][td][0] * linv, o_acc[qs][td][1] * linv);
            w.y = bf2u_rte(o_acc[qs][td][2] * linv, o_acc[qs][td][3] * linv);
            *(uint2*)(op + td * 16) = w;
        }
    }
}

// ---------------------------------------------------------------------------
// Stage 2: C = A @ Wb^T. m97-structure: 128x128 tile, BK=64, double-buffered
// LDS, global_load_lds w16, XOR-swizzled (row&7) 128B rows. Bijective XCD
// grouping: the 8 bn-blocks sharing an A-panel (same bm) land on one XCD.
// ---------------------------------------------------------------------------
__global__ __launch_bounds__(256)
void proj_kernel(const __hip_bfloat16* __restrict__ A,
                 const __hip_bfloat16* __restrict__ Wb,
                 float* __restrict__ C) {
    __shared__ __align__(16) short As[2][128 * 64];  // 32 KB
    __shared__ __align__(16) short Ws[2][128 * 64];  // 32 KB

    const int t = threadIdx.x;
    const int wave = t >> 6, lane = t & 63;
    const int quad = lane >> 4, lr = lane & 15;
    const int wm = wave >> 1, wn = wave & 1;
    const int bx = blockIdx.x;                 // 0..511
    const int xcd = bx & 7, j = bx >> 3;       // j 0..63
    const int bm = (xcd * 8 + (j >> 3)) * 128;
    const int bn = (j & 7) * 128;

    floatx4 acc[4][4] = {};   // [mb][nb]

    auto stage = [&](int buf, int k0) {
#pragma unroll
        for (int c = 0; c < 4; ++c) {
            const int blk = c * 4 + wave;             // 0..15, wave-uniform
            const int r = blk * 8 + (lane >> 3);
            const int g = (lane & 7) ^ (r & 7);
            const __hip_bfloat16* ga = A + (size_t)(bm + r) * Dv + k0 + g * 8;
            const __hip_bfloat16* gw = Wb + (size_t)(bn + r) * Dv + k0 + g * 8;
            __builtin_amdgcn_global_load_lds(
                (const __attribute__((address_space(1))) unsigned int*)(const void*)ga,
                (__attribute__((address_space(3))) unsigned int*)(void*)&As[buf][blk * 512],
                16, 0, 0);
            __builtin_amdgcn_global_load_lds(
                (const __attribute__((address_space(1))) unsigned int*)(const void*)gw,
                (__attribute__((address_space(3))) unsigned int*)(void*)&Ws[buf][blk * 512],
                16, 0, 0);
        }
    };

    stage(0, 0);

#pragma unroll 2
    for (int it = 0; it < Dv / 64; ++it) {
        const int cur = it & 1;
        __syncthreads();                              // drains vmcnt: buf[cur] staged
        if (it + 1 < Dv / 64) stage(1 - cur, (it + 1) * 64);   // overlaps compute

#pragma unroll
        for (int ks = 0; ks < 2; ++ks) {
            short8 af[4];
#pragma unroll
            for (int mb = 0; mb < 4; ++mb) {
                int row = wm * 64 + mb * 16 + lr;
                af[mb] = *(const short8*)&As[cur][row * 64 + (((ks * 4 + quad) ^ (lr & 7)) << 3)];
            }
#pragma unroll
            for (int nb = 0; nb < 4; ++nb) {
                int row = wn * 64 + nb * 16 + lr;
                short8 bf = *(const short8*)&Ws[cur][row * 64 + (((ks * 4 + quad) ^ (lr & 7)) << 3)];
#pragma unroll
                for (int mb = 0; mb < 4; ++mb)
                    acc[mb][nb] = __builtin_amdgcn_mfma_f32_16x16x32_bf16(af[mb], bf, acc[mb][nb], 0, 0, 0);
            }
        }
    }

    // C/D layout: col = lane&15, row = quad*4 + reg
#pragma unroll
    for (int mb = 0; mb < 4; ++mb)
#pragma unroll
        for (int nb = 0; nb < 4; ++nb) {
            int row = bm + wm * 64 + mb * 16 + quad * 4;
            int col = bn + wn * 64 + nb * 16 + lr;
#pragma unroll
            for (int r = 0; r < 4; ++r)
                C[(size_t)(row + r) * Dv + col] = acc[mb][nb][r];
        }
}

// ---------------------------------------------------------------------------
// Stage 3: LayerNorm in place on d_out (fp32). Biased variance, eps=1e-5.
// ---------------------------------------------------------------------------
__global__ __launch_bounds__(256)
void ln_kernel(float* __restrict__ C,
               const float* __restrict__ g) {
    const int row = blockIdx.x;
    const int t = threadIdx.x;
    const int wave = t >> 6, lane = t & 63;

    float* rp = C + (size_t)row * Dv;
    float4 x = *(const float4*)(rp + t * 4);

    float s = x.x + x.y + x.z + x.w;
    float sq = x.x * x.x + x.y * x.y + x.z * x.z + x.w * x.w;
#pragma unroll
    for (int off = 32; off >= 1; off >>= 1) {
        s += __shfl_xor(s, off);
        sq += __shfl_xor(sq, off);
    }
    __shared__ float ss[4], ssq[4];
    if (lane == 0) { ss[wave] = s; ssq[wave] = sq; }
    __syncthreads();
    s = ss[0] + ss[1] + ss[2] + ss[3];
    sq = ssq[0] + ssq[1] + ssq[2] + ssq[3];

    const float rn = 1.f / (float)Dv;
    float mean = s * rn;
    float var = sq * rn - mean * mean;
    float inv = rsqrtf(var + 1e-5f);

    float4 gv = *(const float4*)(g + t * 4);

    float4 o;
    o.x = (x.x - mean) * inv * gv.x;
    o.y = (x.y - mean) * inv * gv.y;
    o.z = (x.z - mean) * inv * gv.z;
    o.w = (x.w - mean) * inv * gv.w;
    *(float4*)(rp + t * 4) = o;
}

// ---------------------------------------------------------------------------
extern "C" void kernel_launch(void* const* d_in, const int* in_sizes, int n_in,
                              void* d_out, int out_size, void* d_ws, size_t ws_size,
                              hipStream_t stream) {
    const float* q = (const float*)d_in[0];
    const float* k = (const float*)d_in[1];
    const float* v = (const float*)d_in[2];
    const float* W = (const float*)d_in[3];
    const float* g = (const float*)d_in[4];
    float* out = (float*)d_out;

    const size_t attnB = (size_t)Bv * Nv * Dv * 2;       // 16 MiB bf16 attn out
    const size_t wbB = (size_t)Dv * Dv * 2;              // 2 MiB bf16 W
    const size_t kbB = (size_t)Bv * Nv * Dv * 2;         // 16 MiB bf16 K

    __hip_bfloat16* attn = (__hip_bfloat16*)d_ws;
    __hip_bfloat16* Wb = (__hip_bfloat16*)((char*)d_ws + attnB);
    __hip_bfloat16* Kb = (__hip_bfloat16*)((char*)d_ws + attnB + wbB);
    __hip_bfloat16* Vtb = (__hip_bfloat16*)((char*)d_ws + attnB + wbB + kbB);

    prep_all<<<KCONV_BLOCKS + WCONV_BLOCKS + VT_BLOCKS, 256, 0, stream>>>(k, Kb, W, Wb, v, Vtb);
    attn_mfma_pre<<<dim3(16, 16, Bv), 256, 0, stream>>>(q, Kb, Vtb, attn);
    proj_kernel<<<512, 256, 0, stream>>>(attn, Wb, out);
    ln_kernel<<<Bv * Nv, 256, 0, stream>>>(out, g);
}

// Round 9
// 288.249 us; speedup vs baseline: 1.1832x; 1.0052x over previous
//
#include <hip/hip_runtime.h>
#include <hip/hip_bf16.h>

// Problem: B=4, N=2048, H=16, Dh=64, D=1024. All global tensors fp32.
// out = LN( softmax(Q K^T / 8) V @ W_out^T ) * g   (fp32 out).
// R15: attn is latency-bound (R14: VALU cut -> VALUBusy down but dur UP;
// occupancy 21%). Fix: QBLK 128->64 (grid 2048 blocks = 8/CU), per-wave
// state halves -> target VGPR<=64 via __launch_bounds__(256,8) -> 8-waves/
// SIMD bucket; LDS 32KB caps 5 blocks/CU = 20 waves/CU (vs ~7 measured).
// Work partition per query identical -> bit-identical output. s_setprio(1)
// around MFMA clusters (T5, +4-7% attn). pk_fma dropped (R14: no benefit,
// costs pair-alignment pressure). prep/proj/ln unchanged (non-attn is
// ~95us fixed harness overhead + ~45us of kernels; not the lever).

#define Bv 4
#define Nv 2048
#define Hv 16
#define DHv 64
#define Dv 1024
#define NT (Nv / 64)

#define KCONV_BLOCKS 4096
#define WCONV_BLOCKS 512
#define VT_BLOCKS 2048

#define L2E 1.44269504088896340736f

typedef __attribute__((ext_vector_type(8))) short short8;
typedef __attribute__((ext_vector_type(4))) float floatx4;

// bf16 pair pack, round-half-up (+0x8000 then take high16 via one v_perm_b32).
__device__ inline unsigned pack_bf2(float a, float b) {
    unsigned ua = __builtin_bit_cast(unsigned, a) + 0x8000u;
    unsigned ub = __builtin_bit_cast(unsigned, b) + 0x8000u;
    return __builtin_amdgcn_perm(ub, ua, 0x07060302u);  // [b.hi16 : a.hi16]
}

// RTE bf16 pair (epilogue, grouped for 8B stores).
__device__ inline unsigned bf2u_rte(float a, float b) {
    unsigned short ua = __builtin_bit_cast(unsigned short, __float2bfloat16(a));
    unsigned short ub = __builtin_bit_cast(unsigned short, __float2bfloat16(b));
    return (unsigned)ua | ((unsigned)ub << 16);
}

// 3-input max; clang fuses nested fmaxf to v_max3_f32 on gfx9+.
__device__ inline float max3f(float a, float b, float c) {
    return fmaxf(fmaxf(a, b), c);
}

__device__ inline void plswap16(unsigned &a, unsigned &b) {
    auto r = __builtin_amdgcn_permlane16_swap(a, b, false, false);
    a = r[0]; b = r[1];
}
__device__ inline void plswap32(unsigned &a, unsigned &b) {
    auto r = __builtin_amdgcn_permlane32_swap(a, b, false, false);
    a = r[0]; b = r[1];
}

// Cross-quad reduce via permlane self-swap (== shfl_xor 16 then 32).
__device__ inline float redq_max(float x) {
    unsigned a = __builtin_bit_cast(unsigned, x), b = a;
    plswap16(a, b);
    float m = fmaxf(__builtin_bit_cast(float, a), __builtin_bit_cast(float, b));
    unsigned c = __builtin_bit_cast(unsigned, m), d = c;
    plswap32(c, d);
    return fmaxf(__builtin_bit_cast(float, c), __builtin_bit_cast(float, d));
}
__device__ inline float redq_sum(float x) {
    unsigned a = __builtin_bit_cast(unsigned, x), b = a;
    plswap16(a, b);
    float m = __builtin_bit_cast(float, a) + __builtin_bit_cast(float, b);
    unsigned c = __builtin_bit_cast(unsigned, m), d = c;
    plswap32(c, d);
    return __builtin_bit_cast(float, c) + __builtin_bit_cast(float, d);
}

// ---------------------------------------------------------------------------
// Fused prep (one launch): K f32->bf16 (4096 blk), W f32->bf16 (512 blk),
// V f32 -> V^T bf16 [b][h][64][2048] (2048 blk). pack_bf2 rounding keeps all
// downstream operand bits identical.
// ---------------------------------------------------------------------------
__global__ __launch_bounds__(256)
void prep_all(const float* __restrict__ K, __hip_bfloat16* __restrict__ Kb,
              const float* __restrict__ W, __hip_bfloat16* __restrict__ Wb,
              const float* __restrict__ v, __hip_bfloat16* __restrict__ vt) {
    __shared__ short T[64][76];   // vtrans scratch (+12 pad)
    int bid = blockIdx.x;
    if (bid < KCONV_BLOCKS + WCONV_BLOCKS) {
        const float* src;
        __hip_bfloat16* dst;
        if (bid < KCONV_BLOCKS) { src = K; dst = Kb; }
        else { src = W; dst = Wb; bid -= KCONV_BLOCKS; }
        int base = (bid * 256 + threadIdx.x) * 8;
        float4 f0 = *(const float4*)(src + base);
        float4 f1 = *(const float4*)(src + base + 4);
        uint4 u;
        u.x = pack_bf2(f0.x, f0.y);
        u.y = pack_bf2(f0.z, f0.w);
        u.z = pack_bf2(f1.x, f1.y);
        u.w = pack_bf2(f1.z, f1.w);
        *(uint4*)(dst + base) = u;
        return;
    }
    bid -= KCONV_BLOCKS + WCONV_BLOCKS;        // 0..2047
    const int b = bid >> 9;                    // 512 per batch
    const int rem = bid & 511;
    const int h = rem >> 5;                    // 16 heads
    const int n0 = (rem & 31) * 64;            // 32 n-tiles
    const int t = threadIdx.x;
    const int ir = t >> 4;
    const int d4 = (t & 15) * 4;
#pragma unroll
    for (int pass = 0; pass < 4; ++pass) {
        int n = pass * 16 + ir;
        float4 f = *(const float4*)(v + ((size_t)b * Nv + n0 + n) * Dv + h * DHv + d4);
        T[d4 + 0][n] = (short)(pack_bf2(f.x, f.x) & 0xffffu);
        T[d4 + 1][n] = (short)(pack_bf2(f.y, f.y) & 0xffffu);
        T[d4 + 2][n] = (short)(pack_bf2(f.z, f.z) & 0xffffu);
        T[d4 + 3][n] = (short)(pack_bf2(f.w, f.w) & 0xffffu);
    }
    __syncthreads();
    const int d = t >> 2, kg = (t & 3) * 16;
    unsigned u[8];
#pragma unroll
    for (int i = 0; i < 8; ++i)
        u[i] = (unsigned)(unsigned short)T[d][kg + 2 * i] |
               ((unsigned)(unsigned short)T[d][kg + 2 * i + 1] << 16);
    __hip_bfloat16* op = vt + ((size_t)(b * Hv + h) * DHv + d) * Nv + n0 + kg;
    *(uint4*)op = *(uint4*)&u[0];
    *(uint4*)(op + 8) = *(uint4*)&u[4];
}

// ---------------------------------------------------------------------------
// MFMA flash attention, prep-fed, O^T accumulation. QBLK=64: block = 256 thr
// (4 waves) = 64 queries of one (b,h); wave owns 16 queries (lane = query).
// Grid 2048 blocks -> 8/CU dispatched; LDS 32KB -> 5 blocks/CU resident;
// VGPR target <=64 (launch_bounds 256,8) -> 20 waves/CU for latency hiding.
// K / V^T staged via global_load_lds w16 (source-side inverse XOR swizzle).
// Softmax cross-lane via permlane; alpha/linv lane-local (O^T).
// ---------------------------------------------------------------------------
__global__ __launch_bounds__(256, 8)
void attn_mfma_pre(const float* __restrict__ q,
                   const __hip_bfloat16* __restrict__ Kb,
                   const __hip_bfloat16* __restrict__ Vtb,
                   __hip_bfloat16* __restrict__ out) {
    __shared__ __align__(16) short Kt[2][64 * 64];   // 16 KB
    __shared__ __align__(16) short Vt[2][64 * 64];   // 16 KB (V^T: rows = d)

    const int t = threadIdx.x;
    const int wave = t >> 6, lane = t & 63;
    const int quad = lane >> 4, lr = lane & 15;
    const int b = blockIdx.z;
    // bijective XCD swizzle over (qtile,head): same-h blocks -> same XCD.
    const int lid2 = blockIdx.y * 32 + blockIdx.x;   // 0..511
    const int xcd = lid2 & 7, jj = lid2 >> 3;        // jj 0..63
    const int h = xcd * 2 + (jj >> 5);
    const int q0 = (jj & 31) * 64;
    const size_t qbh = ((size_t)b * Nv) * Dv + h * DHv;
    const __hip_bfloat16* kb = Kb + (size_t)b * Nv * Dv + h * DHv;
    const __hip_bfloat16* vtb = Vtb + (size_t)(b * Hv + h) * DHv * Nv;

    const int srow = lane >> 3;   // row within 8-row chunk
    const int sg = lane & 7;      // stored group
    auto stage = [&](int buf, int k0) {
#pragma unroll
        for (int c = 0; c < 2; ++c) {
            int blk = wave * 2 + c;          // 0..7, wave-uniform
            int r = blk * 8 + srow;
            int g = sg ^ (r & 7);            // inverse swizzle on source
            __builtin_amdgcn_global_load_lds(
                (const __attribute__((address_space(1))) unsigned*)(const void*)
                    (kb + (size_t)(k0 + r) * Dv + g * 8),
                (__attribute__((address_space(3))) unsigned*)(void*)&Kt[buf][blk * 512],
                16, 0, 0);
            __builtin_amdgcn_global_load_lds(
                (const __attribute__((address_space(1))) unsigned*)(const void*)
                    (vtb + (size_t)r * Nv + k0 + g * 8),
                (__attribute__((address_space(3))) unsigned*)(void*)&Vt[buf][blk * 512],
                16, 0, 0);
        }
    };

    stage(0, 0);   // K/V tile-0 DMA in flight first

    // ---- Q fragments direct from global (once), scale 0.125 exact ----
    short8 qfrag[2];   // [kh]: Q[q = q0+wave*16+lr][d = 32kh+8quad+j]
#pragma unroll
    for (int kh = 0; kh < 2; ++kh) {
        int row = q0 + wave * 16 + lr;
        const float* qp = q + qbh + (size_t)row * Dv + kh * 32 + quad * 8;
        float4 f0 = *(const float4*)qp;
        float4 f1 = *(const float4*)(qp + 4);
        int4 qi;
        qi.x = (int)pack_bf2(f0.x * 0.125f, f0.y * 0.125f);
        qi.y = (int)pack_bf2(f0.z * 0.125f, f0.w * 0.125f);
        qi.z = (int)pack_bf2(f1.x * 0.125f, f1.y * 0.125f);
        qi.w = (int)pack_bf2(f1.z * 0.125f, f1.w * 0.125f);
        qfrag[kh] = __builtin_bit_cast(short8, qi);
    }

    floatx4 o_acc[4] = {};           // O^T: [td]: O[q=lr][d=16td+4quad+r]
    float mrow = -INFINITY;          // per-query (lane-local, lr)
    float lrow = 0.f;

#pragma unroll 2
    for (int it = 0; it < NT; ++it) {
        const int cur = it & 1;                  // compile-time under unroll 2
        __syncthreads();                         // vmcnt drained: buf[cur] staged
        if (it + 1 < NT) stage(1 - cur, (it + 1) * 64);   // latency hidden by compute

        // ---- S^T = K·Q^T ----
        floatx4 s_acc[4] = {};
        __builtin_amdgcn_s_setprio(1);
#pragma unroll
        for (int tt = 0; tt < 4; ++tt) {
            int row = tt * 16 + lr;
            short8 kf0 = *(const short8*)&Kt[cur][row * 64 + ((quad ^ (lr & 7)) << 3)];
            short8 kf1 = *(const short8*)&Kt[cur][row * 64 + (((4 + quad) ^ (lr & 7)) << 3)];
            s_acc[tt] = __builtin_amdgcn_mfma_f32_16x16x32_bf16(kf0, qfrag[0], s_acc[tt], 0, 0, 0);
            s_acc[tt] = __builtin_amdgcn_mfma_f32_16x16x32_bf16(kf1, qfrag[1], s_acc[tt], 0, 0, 0);
        }
        __builtin_amdgcn_s_setprio(0);

        // ---- online softmax (defer-max) + P pack ----
        // 16-value max via max3 triples (commutative reorder only).
        float m0 = max3f(s_acc[0][0], s_acc[0][1], s_acc[0][2]);
        float m1 = max3f(s_acc[0][3], s_acc[1][0], s_acc[1][1]);
        float m2 = max3f(s_acc[1][2], s_acc[1][3], s_acc[2][0]);
        float m3 = max3f(s_acc[2][1], s_acc[2][2], s_acc[2][3]);
        float m4 = max3f(s_acc[3][0], s_acc[3][1], s_acc[3][2]);
        float m5 = max3f(m0, m1, s_acc[3][3]);
        float tmax = redq_max(max3f(m5, max3f(m2, m3, m4), -INFINITY));
        // defer-max: only rescale when some query's max grew past THR=8.
        if (!__all(tmax <= mrow + 8.0f)) {
            float mnew = fmaxf(mrow, tmax);
            float alpha = __expf(mrow - mnew);   // first tile: exp(-inf)=0
            mrow = mnew;
            lrow *= alpha;
#pragma unroll
            for (int td = 0; td < 4; ++td)
#pragma unroll
                for (int r2 = 0; r2 < 4; ++r2) o_acc[td][r2] *= alpha;  // lane-local
        }
        float negmc = -(mrow * L2E);
        unsigned p2[8];
        float psum = 0.f;
#pragma unroll
        for (int tt = 0; tt < 4; ++tt) {
            float p0 = __builtin_amdgcn_exp2f(__builtin_fmaf(s_acc[tt][0], L2E, negmc));
            float p1 = __builtin_amdgcn_exp2f(__builtin_fmaf(s_acc[tt][1], L2E, negmc));
            float pa = __builtin_amdgcn_exp2f(__builtin_fmaf(s_acc[tt][2], L2E, negmc));
            float pb = __builtin_amdgcn_exp2f(__builtin_fmaf(s_acc[tt][3], L2E, negmc));
            psum += (p0 + p1) + (pa + pb);
            p2[tt * 2 + 0] = pack_bf2(p0, p1);
            p2[tt * 2 + 1] = pack_bf2(pa, pb);
        }
        lrow += redq_sum(psum);

        // ---- PV as O^T += V^T·P^T: mfma(V_frag, P_frag). P-gather per pair
        // (x,y): swap32 -> a=[x.lo,y.lo] b=[x.hi,y.hi]; swap16 ->
        // a=[x0,x2,y0,y2] b=[x1,x3,y1,y3] == srcA/srcB words. ----
#pragma unroll
        for (int kh = 0; kh < 2; ++kh) {
            int tlo = 4 * kh, thi = 4 * kh + 2;
            unsigned a0 = p2[tlo + 0], b0 = p2[thi + 0];
            unsigned a1 = p2[tlo + 1], b1 = p2[thi + 1];
            plswap32(a0, b0);
            plswap16(a0, b0);
            plswap32(a1, b1);
            plswap16(a1, b1);
            int4 afi;
            afi.x = (int)a0;
            afi.y = (int)a1;
            afi.z = (int)b0;
            afi.w = (int)b1;
            short8 af = __builtin_bit_cast(short8, afi);
            __builtin_amdgcn_s_setprio(1);
#pragma unroll
            for (int td = 0; td < 4; ++td) {
                int d = td * 16 + lr;
                short8 vf = *(const short8*)&Vt[cur][d * 64 + (((kh * 4 + quad) ^ (lr & 7)) << 3)];
                o_acc[td] = __builtin_amdgcn_mfma_f32_16x16x32_bf16(vf, af, o_acc[td], 0, 0, 0);
            }
            __builtin_amdgcn_s_setprio(0);
        }
    }

    // ---- epilogue (O^T): lane owns query q = q0+wave*16+lr;
    // d = td*16 + quad*4 + r2 -> 8B grouped stores. linv lane-local. ----
    {
        float linv = 1.f / lrow;
        int qrow = q0 + wave * 16 + lr;
        __hip_bfloat16* op = out + ((size_t)(b * Nv + qrow)) * Dv + h * DHv + quad * 4;
#pragma unroll
        for (int td = 0; td < 4; ++td) {
            uint2 w;
            w.x = bf2u_rte(o_acc[td][0] * linv, o_acc[td][1] * linv);
            w.y = bf2u_rte(o_acc[td][2] * linv, o_acc[td][3] * linv);
            *(uint2*)(op + td * 16) = w;
        }
    }
}

// ---------------------------------------------------------------------------
// Stage 2: C = A @ Wb^T. m97-structure: 128x128 tile, BK=64, double-buffered
// LDS, global_load_lds w16, XOR-swizzled (row&7) 128B rows. Bijective XCD
// grouping: the 8 bn-blocks sharing an A-panel (same bm) land on one XCD.
// ---------------------------------------------------------------------------
__global__ __launch_bounds__(256)
void proj_kernel(const __hip_bfloat16* __restrict__ A,
                 const __hip_bfloat16* __restrict__ Wb,
                 float* __restrict__ C) {
    __shared__ __align__(16) short As[2][128 * 64];  // 32 KB
    __shared__ __align__(16) short Ws[2][128 * 64];  // 32 KB

    const int t = threadIdx.x;
    const int wave = t >> 6, lane = t & 63;
    const int quad = lane >> 4, lr = lane & 15;
    const int wm = wave >> 1, wn = wave & 1;
    const int bx = blockIdx.x;                 // 0..511
    const int xcd = bx & 7, j = bx >> 3;       // j 0..63
    const int bm = (xcd * 8 + (j >> 3)) * 128;
    const int bn = (j & 7) * 128;

    floatx4 acc[4][4] = {};   // [mb][nb]

    auto stage = [&](int buf, int k0) {
#pragma unroll
        for (int c = 0; c < 4; ++c) {
            const int blk = c * 4 + wave;             // 0..15, wave-uniform
            const int r = blk * 8 + (lane >> 3);
            const int g = (lane & 7) ^ (r & 7);
            const __hip_bfloat16* ga = A + (size_t)(bm + r) * Dv + k0 + g * 8;
            const __hip_bfloat16* gw = Wb + (size_t)(bn + r) * Dv + k0 + g * 8;
            __builtin_amdgcn_global_load_lds(
                (const __attribute__((address_space(1))) unsigned int*)(const void*)ga,
                (__attribute__((address_space(3))) unsigned int*)(void*)&As[buf][blk * 512],
                16, 0, 0);
            __builtin_amdgcn_global_load_lds(
                (const __attribute__((address_space(1))) unsigned int*)(const void*)gw,
                (__attribute__((address_space(3))) unsigned int*)(void*)&Ws[buf][blk * 512],
                16, 0, 0);
        }
    };

    stage(0, 0);

#pragma unroll 2
    for (int it = 0; it < Dv / 64; ++it) {
        const int cur = it & 1;
        __syncthreads();                              // drains vmcnt: buf[cur] staged
        if (it + 1 < Dv / 64) stage(1 - cur, (it + 1) * 64);   // overlaps compute

#pragma unroll
        for (int ks = 0; ks < 2; ++ks) {
            short8 af[4];
#pragma unroll
            for (int mb = 0; mb < 4; ++mb) {
                int row = wm * 64 + mb * 16 + lr;
                af[mb] = *(const short8*)&As[cur][row * 64 + (((ks * 4 + quad) ^ (lr & 7)) << 3)];
            }
#pragma unroll
            for (int nb = 0; nb < 4; ++nb) {
                int row = wn * 64 + nb * 16 + lr;
                short8 bf = *(const short8*)&Ws[cur][row * 64 + (((ks * 4 + quad) ^ (lr & 7)) << 3)];
#pragma unroll
                for (int mb = 0; mb < 4; ++mb)
                    acc[mb][nb] = __builtin_amdgcn_mfma_f32_16x16x32_bf16(af[mb], bf, acc[mb][nb], 0, 0, 0);
            }
        }
    }

    // C/D layout: col = lane&15, row = quad*4 + reg
#pragma unroll
    for (int mb = 0; mb < 4; ++mb)
#pragma unroll
        for (int nb = 0; nb < 4; ++nb) {
            int row = bm + wm * 64 + mb * 16 + quad * 4;
            int col = bn + wn * 64 + nb * 16 + lr;
#pragma unroll
            for (int r = 0; r < 4; ++r)
                C[(size_t)(row + r) * Dv + col] = acc[mb][nb][r];
        }
}

// ---------------------------------------------------------------------------
// Stage 3: LayerNorm in place on d_out (fp32). Biased variance, eps=1e-5.
// ---------------------------------------------------------------------------
__global__ __launch_bounds__(256)
void ln_kernel(float* __restrict__ C,
               const float* __restrict__ g) {
    const int row = blockIdx.x;
    const int t = threadIdx.x;
    const int wave = t >> 6, lane = t & 63;

    float* rp = C + (size_t)row * Dv;
    float4 x = *(const float4*)(rp + t * 4);

    float s = x.x + x.y + x.z + x.w;
    float sq = x.x * x.x + x.y * x.y + x.z * x.z + x.w * x.w;
#pragma unroll
    for (int off = 32; off >= 1; off >>= 1) {
        s += __shfl_xor(s, off);
        sq += __shfl_xor(sq, off);
    }
    __shared__ float ss[4], ssq[4];
    if (lane == 0) { ss[wave] = s; ssq[wave] = sq; }
    __syncthreads();
    s = ss[0] + ss[1] + ss[2] + ss[3];
    sq = ssq[0] + ssq[1] + ssq[2] + ssq[3];

    const float rn = 1.f / (float)Dv;
    float mean = s * rn;
    float var = sq * rn - mean * mean;
    float inv = rsqrtf(var + 1e-5f);

    float4 gv = *(const float4*)(g + t * 4);

    float4 o;
    o.x = (x.x - mean) * inv * gv.x;
    o.y = (x.y - mean) * inv * gv.y;
    o.z = (x.z - mean) * inv * gv.z;
    o.w = (x.w - mean) * inv * gv.w;
    *(float4*)(rp + t * 4) = o;
}

// ---------------------------------------------------------------------------
extern "C" void kernel_launch(void* const* d_in, const int* in_sizes, int n_in,
                              void* d_out, int out_size, void* d_ws, size_t ws_size,
                              hipStream_t stream) {
    const float* q = (const float*)d_in[0];
    const float* k = (const float*)d_in[1];
    const float* v = (const float*)d_in[2];
    const float* W = (const float*)d_in[3];
    const float* g = (const float*)d_in[4];
    float* out = (float*)d_out;

    const size_t attnB = (size_t)Bv * Nv * Dv * 2;       // 16 MiB bf16 attn out
    const size_t wbB = (size_t)Dv * Dv * 2;              // 2 MiB bf16 W
    const size_t kbB = (size_t)Bv * Nv * Dv * 2;         // 16 MiB bf16 K

    __hip_bfloat16* attn = (__hip_bfloat16*)d_ws;
    __hip_bfloat16* Wb = (__hip_bfloat16*)((char*)d_ws + attnB);
    __hip_bfloat16* Kb = (__hip_bfloat16*)((char*)d_ws + attnB + wbB);
    __hip_bfloat16* Vtb = (__hip_bfloat16*)((char*)d_ws + attnB + wbB + kbB);

    prep_all<<<KCONV_BLOCKS + WCONV_BLOCKS + VT_BLOCKS, 256, 0, stream>>>(k, Kb, W, Wb, v, Vtb);
    attn_mfma_pre<<<dim3(32, 16, Bv), 256, 0, stream>>>(q, Kb, Vtb, attn);
    proj_kernel<<<512, 256, 0, stream>>>(attn, Wb, out);
    ln_kernel<<<Bv * Nv, 256, 0, stream>>>(out, g);
}

// Round 10
// 271.972 us; speedup vs baseline: 1.2540x; 1.0598x over previous
//
#include <hip/hip_runtime.h>
#include <hip/hip_bf16.h>

// Problem: B=4, N=2048, H=16, Dh=64, D=1024. All global tensors fp32.
// out = LN( softmax(Q K^T / 8) V @ W_out^T ) * g   (fp32 out).
// R16: attn VALU diet, shifting work to the 22%-utilized MFMA pipe:
//  (1) ones-row PV trick: l = sum_k P computed by one extra
//      mfma(ones_frag, P_frag, lsum) per kh (ones_frag = register constant,
//      lr==0 lanes hold 1.0bf16). Removes the 16-add psum chain + redq_sum.
//      alpha-rescale covers lsum in the same lane-local loop; epilogue
//      broadcasts 1/l with one __shfl. l now sums bf16(P) — consistent
//      with the PV numerator.
//  (2) P pack via v_cvt_pk_bf16_f32 (1 instr/pair vs 3; RTE rounding).
// Both change output by ulp-class only. QBLK=64 / occupancy structure,
// prep/proj/ln unchanged from R15 (verified 288us, attn 132us).

#define Bv 4
#define Nv 2048
#define Hv 16
#define DHv 64
#define Dv 1024
#define NT (Nv / 64)

#define KCONV_BLOCKS 4096
#define WCONV_BLOCKS 512
#define VT_BLOCKS 2048

#define L2E 1.44269504088896340736f

typedef __attribute__((ext_vector_type(8))) short short8;
typedef __attribute__((ext_vector_type(4))) float floatx4;

// bf16 pair pack, round-half-up (+0x8000 then take high16 via one v_perm_b32).
__device__ inline unsigned pack_bf2(float a, float b) {
    unsigned ua = __builtin_bit_cast(unsigned, a) + 0x8000u;
    unsigned ub = __builtin_bit_cast(unsigned, b) + 0x8000u;
    return __builtin_amdgcn_perm(ub, ua, 0x07060302u);  // [b.hi16 : a.hi16]
}

// Packed f32->bf16x2 convert, RTE (1 VALU instr). dst = [bf16(b) : bf16(a)].
__device__ inline unsigned cvt_pk_bf16(float a, float b) {
    unsigned d;
    asm("v_cvt_pk_bf16_f32 %0, %1, %2" : "=v"(d) : "v"(a), "v"(b));
    return d;
}

// RTE bf16 pair (epilogue, grouped for 8B stores).
__device__ inline unsigned bf2u_rte(float a, float b) {
    unsigned short ua = __builtin_bit_cast(unsigned short, __float2bfloat16(a));
    unsigned short ub = __builtin_bit_cast(unsigned short, __float2bfloat16(b));
    return (unsigned)ua | ((unsigned)ub << 16);
}

// 3-input max; clang fuses nested fmaxf to v_max3_f32 on gfx9+.
__device__ inline float max3f(float a, float b, float c) {
    return fmaxf(fmaxf(a, b), c);
}

__device__ inline void plswap16(unsigned &a, unsigned &b) {
    auto r = __builtin_amdgcn_permlane16_swap(a, b, false, false);
    a = r[0]; b = r[1];
}
__device__ inline void plswap32(unsigned &a, unsigned &b) {
    auto r = __builtin_amdgcn_permlane32_swap(a, b, false, false);
    a = r[0]; b = r[1];
}

// Cross-quad max via permlane self-swap (== shfl_xor 16 then 32).
__device__ inline float redq_max(float x) {
    unsigned a = __builtin_bit_cast(unsigned, x), b = a;
    plswap16(a, b);
    float m = fmaxf(__builtin_bit_cast(float, a), __builtin_bit_cast(float, b));
    unsigned c = __builtin_bit_cast(unsigned, m), d = c;
    plswap32(c, d);
    return fmaxf(__builtin_bit_cast(float, c), __builtin_bit_cast(float, d));
}

// ---------------------------------------------------------------------------
// Fused prep (one launch): K f32->bf16 (4096 blk), W f32->bf16 (512 blk),
// V f32 -> V^T bf16 [b][h][64][2048] (2048 blk). pack_bf2 rounding keeps all
// downstream operand bits identical.
// ---------------------------------------------------------------------------
__global__ __launch_bounds__(256)
void prep_all(const float* __restrict__ K, __hip_bfloat16* __restrict__ Kb,
              const float* __restrict__ W, __hip_bfloat16* __restrict__ Wb,
              const float* __restrict__ v, __hip_bfloat16* __restrict__ vt) {
    __shared__ short T[64][76];   // vtrans scratch (+12 pad)
    int bid = blockIdx.x;
    if (bid < KCONV_BLOCKS + WCONV_BLOCKS) {
        const float* src;
        __hip_bfloat16* dst;
        if (bid < KCONV_BLOCKS) { src = K; dst = Kb; }
        else { src = W; dst = Wb; bid -= KCONV_BLOCKS; }
        int base = (bid * 256 + threadIdx.x) * 8;
        float4 f0 = *(const float4*)(src + base);
        float4 f1 = *(const float4*)(src + base + 4);
        uint4 u;
        u.x = pack_bf2(f0.x, f0.y);
        u.y = pack_bf2(f0.z, f0.w);
        u.z = pack_bf2(f1.x, f1.y);
        u.w = pack_bf2(f1.z, f1.w);
        *(uint4*)(dst + base) = u;
        return;
    }
    bid -= KCONV_BLOCKS + WCONV_BLOCKS;        // 0..2047
    const int b = bid >> 9;                    // 512 per batch
    const int rem = bid & 511;
    const int h = rem >> 5;                    // 16 heads
    const int n0 = (rem & 31) * 64;            // 32 n-tiles
    const int t = threadIdx.x;
    const int ir = t >> 4;
    const int d4 = (t & 15) * 4;
#pragma unroll
    for (int pass = 0; pass < 4; ++pass) {
        int n = pass * 16 + ir;
        float4 f = *(const float4*)(v + ((size_t)b * Nv + n0 + n) * Dv + h * DHv + d4);
        T[d4 + 0][n] = (short)(pack_bf2(f.x, f.x) & 0xffffu);
        T[d4 + 1][n] = (short)(pack_bf2(f.y, f.y) & 0xffffu);
        T[d4 + 2][n] = (short)(pack_bf2(f.z, f.z) & 0xffffu);
        T[d4 + 3][n] = (short)(pack_bf2(f.w, f.w) & 0xffffu);
    }
    __syncthreads();
    const int d = t >> 2, kg = (t & 3) * 16;
    unsigned u[8];
#pragma unroll
    for (int i = 0; i < 8; ++i)
        u[i] = (unsigned)(unsigned short)T[d][kg + 2 * i] |
               ((unsigned)(unsigned short)T[d][kg + 2 * i + 1] << 16);
    __hip_bfloat16* op = vt + ((size_t)(b * Hv + h) * DHv + d) * Nv + n0 + kg;
    *(uint4*)op = *(uint4*)&u[0];
    *(uint4*)(op + 8) = *(uint4*)&u[4];
}

// ---------------------------------------------------------------------------
// MFMA flash attention, prep-fed, O^T accumulation. QBLK=64: block = 256 thr
// (4 waves) = 64 queries of one (b,h); wave owns 16 queries (lane = query).
// K / V^T staged via global_load_lds w16 (source-side inverse XOR swizzle).
// Softmax cross-lane via permlane; alpha/linv lane-local (O^T). l computed
// by ones-row MFMA; P packed with v_cvt_pk_bf16_f32.
// ---------------------------------------------------------------------------
__global__ __launch_bounds__(256, 8)
void attn_mfma_pre(const float* __restrict__ q,
                   const __hip_bfloat16* __restrict__ Kb,
                   const __hip_bfloat16* __restrict__ Vtb,
                   __hip_bfloat16* __restrict__ out) {
    __shared__ __align__(16) short Kt[2][64 * 64];   // 16 KB
    __shared__ __align__(16) short Vt[2][64 * 64];   // 16 KB (V^T: rows = d)

    const int t = threadIdx.x;
    const int wave = t >> 6, lane = t & 63;
    const int quad = lane >> 4, lr = lane & 15;
    const int b = blockIdx.z;
    // bijective XCD swizzle over (qtile,head): same-h blocks -> same XCD.
    const int lid2 = blockIdx.y * 32 + blockIdx.x;   // 0..511
    const int xcd = lid2 & 7, jj = lid2 >> 3;        // jj 0..63
    const int h = xcd * 2 + (jj >> 5);
    const int q0 = (jj & 31) * 64;
    const size_t qbh = ((size_t)b * Nv) * Dv + h * DHv;
    const __hip_bfloat16* kb = Kb + (size_t)b * Nv * Dv + h * DHv;
    const __hip_bfloat16* vtb = Vtb + (size_t)(b * Hv + h) * DHv * Nv;

    const int srow = lane >> 3;   // row within 8-row chunk
    const int sg = lane & 7;      // stored group
    auto stage = [&](int buf, int k0) {
#pragma unroll
        for (int c = 0; c < 2; ++c) {
            int blk = wave * 2 + c;          // 0..7, wave-uniform
            int r = blk * 8 + srow;
            int g = sg ^ (r & 7);            // inverse swizzle on source
            __builtin_amdgcn_global_load_lds(
                (const __attribute__((address_space(1))) unsigned*)(const void*)
                    (kb + (size_t)(k0 + r) * Dv + g * 8),
                (__attribute__((address_space(3))) unsigned*)(void*)&Kt[buf][blk * 512],
                16, 0, 0);
            __builtin_amdgcn_global_load_lds(
                (const __attribute__((address_space(1))) unsigned*)(const void*)
                    (vtb + (size_t)r * Nv + k0 + g * 8),
                (__attribute__((address_space(3))) unsigned*)(void*)&Vt[buf][blk * 512],
                16, 0, 0);
        }
    };

    stage(0, 0);   // K/V tile-0 DMA in flight first

    // ---- Q fragments direct from global (once), scale 0.125 exact ----
    short8 qfrag[2];   // [kh]: Q[q = q0+wave*16+lr][d = 32kh+8quad+j]
#pragma unroll
    for (int kh = 0; kh < 2; ++kh) {
        int row = q0 + wave * 16 + lr;
        const float* qp = q + qbh + (size_t)row * Dv + kh * 32 + quad * 8;
        float4 f0 = *(const float4*)qp;
        float4 f1 = *(const float4*)(qp + 4);
        int4 qi;
        qi.x = (int)pack_bf2(f0.x * 0.125f, f0.y * 0.125f);
        qi.y = (int)pack_bf2(f0.z * 0.125f, f0.w * 0.125f);
        qi.z = (int)pack_bf2(f1.x * 0.125f, f1.y * 0.125f);
        qi.w = (int)pack_bf2(f1.z * 0.125f, f1.w * 0.125f);
        qfrag[kh] = __builtin_bit_cast(short8, qi);
    }

    // ones-row A-fragment: A[m][k] = (m==0) ? 1.0bf16 : 0. m = lane&15.
    short8 ones_f;
    {
        unsigned w = (lr == 0) ? 0x3F803F80u : 0u;
        int4 oi = {(int)w, (int)w, (int)w, (int)w};
        ones_f = __builtin_bit_cast(short8, oi);
    }

    floatx4 o_acc[4] = {};           // O^T: [td]: O[q=lr][d=16td+4quad+r]
    floatx4 lsum = {};               // lsum[0] on lanes 0-15 = l(query=lr)
    float mrow = -INFINITY;          // per-query (lane-local, lr)

#pragma unroll 2
    for (int it = 0; it < NT; ++it) {
        const int cur = it & 1;                  // compile-time under unroll 2
        __syncthreads();                         // vmcnt drained: buf[cur] staged
        if (it + 1 < NT) stage(1 - cur, (it + 1) * 64);   // latency hidden by compute

        // ---- S^T = K·Q^T ----
        floatx4 s_acc[4] = {};
        __builtin_amdgcn_s_setprio(1);
#pragma unroll
        for (int tt = 0; tt < 4; ++tt) {
            int row = tt * 16 + lr;
            short8 kf0 = *(const short8*)&Kt[cur][row * 64 + ((quad ^ (lr & 7)) << 3)];
            short8 kf1 = *(const short8*)&Kt[cur][row * 64 + (((4 + quad) ^ (lr & 7)) << 3)];
            s_acc[tt] = __builtin_amdgcn_mfma_f32_16x16x32_bf16(kf0, qfrag[0], s_acc[tt], 0, 0, 0);
            s_acc[tt] = __builtin_amdgcn_mfma_f32_16x16x32_bf16(kf1, qfrag[1], s_acc[tt], 0, 0, 0);
        }
        __builtin_amdgcn_s_setprio(0);

        // ---- online softmax (defer-max) + P pack ----
        float m0 = max3f(s_acc[0][0], s_acc[0][1], s_acc[0][2]);
        float m1 = max3f(s_acc[0][3], s_acc[1][0], s_acc[1][1]);
        float m2 = max3f(s_acc[1][2], s_acc[1][3], s_acc[2][0]);
        float m3 = max3f(s_acc[2][1], s_acc[2][2], s_acc[2][3]);
        float m4 = max3f(s_acc[3][0], s_acc[3][1], s_acc[3][2]);
        float m5 = max3f(m0, m1, s_acc[3][3]);
        float tmax = redq_max(max3f(m5, max3f(m2, m3, m4), -INFINITY));
        // defer-max: only rescale when some query's max grew past THR=8.
        if (!__all(tmax <= mrow + 8.0f)) {
            float mnew = fmaxf(mrow, tmax);
            float alpha = __expf(mrow - mnew);   // first tile: exp(-inf)=0
            mrow = mnew;
            lsum[0] *= alpha;                    // lane-local (lanes 0-15 carry l)
#pragma unroll
            for (int td = 0; td < 4; ++td)
#pragma unroll
                for (int r2 = 0; r2 < 4; ++r2) o_acc[td][r2] *= alpha;  // lane-local
        }
        float negmc = -(mrow * L2E);
        unsigned p2[8];
#pragma unroll
        for (int tt = 0; tt < 4; ++tt) {
            float p0 = __builtin_amdgcn_exp2f(__builtin_fmaf(s_acc[tt][0], L2E, negmc));
            float p1 = __builtin_amdgcn_exp2f(__builtin_fmaf(s_acc[tt][1], L2E, negmc));
            float pa = __builtin_amdgcn_exp2f(__builtin_fmaf(s_acc[tt][2], L2E, negmc));
            float pb = __builtin_amdgcn_exp2f(__builtin_fmaf(s_acc[tt][3], L2E, negmc));
            p2[tt * 2 + 0] = cvt_pk_bf16(p0, p1);
            p2[tt * 2 + 1] = cvt_pk_bf16(pa, pb);
        }

        // ---- PV as O^T += V^T·P^T: mfma(V_frag, P_frag). P-gather per pair
        // (x,y): swap32 -> a=[x.lo,y.lo] b=[x.hi,y.hi]; swap16 ->
        // a=[x0,x2,y0,y2] b=[x1,x3,y1,y3] == srcA/srcB words.
        // l rides the MFMA pipe: lsum += ones_row . P  (row 0 = sum over k). ----
#pragma unroll
        for (int kh = 0; kh < 2; ++kh) {
            int tlo = 4 * kh, thi = 4 * kh + 2;
            unsigned a0 = p2[tlo + 0], b0 = p2[thi + 0];
            unsigned a1 = p2[tlo + 1], b1 = p2[thi + 1];
            plswap32(a0, b0);
            plswap16(a0, b0);
            plswap32(a1, b1);
            plswap16(a1, b1);
            int4 afi;
            afi.x = (int)a0;
            afi.y = (int)a1;
            afi.z = (int)b0;
            afi.w = (int)b1;
            short8 af = __builtin_bit_cast(short8, afi);
            __builtin_amdgcn_s_setprio(1);
#pragma unroll
            for (int td = 0; td < 4; ++td) {
                int d = td * 16 + lr;
                short8 vf = *(const short8*)&Vt[cur][d * 64 + (((kh * 4 + quad) ^ (lr & 7)) << 3)];
                o_acc[td] = __builtin_amdgcn_mfma_f32_16x16x32_bf16(vf, af, o_acc[td], 0, 0, 0);
            }
            lsum = __builtin_amdgcn_mfma_f32_16x16x32_bf16(ones_f, af, lsum, 0, 0, 0);
            __builtin_amdgcn_s_setprio(0);
        }
    }

    // ---- epilogue (O^T): lane owns query q = q0+wave*16+lr.
    // l(q) lives in lsum[0] of lane q (quad 0); broadcast via one shfl. ----
    {
        float linv = __shfl(1.f / lsum[0], lr);
        int qrow = q0 + wave * 16 + lr;
        __hip_bfloat16* op = out + ((size_t)(b * Nv + qrow)) * Dv + h * DHv + quad * 4;
#pragma unroll
        for (int td = 0; td < 4; ++td) {
            uint2 w;
            w.x = bf2u_rte(o_acc[td][0] * linv, o_acc[td][1] * linv);
            w.y = bf2u_rte(o_acc[td][2] * linv, o_acc[td][3] * linv);
            *(uint2*)(op + td * 16) = w;
        }
    }
}

// ---------------------------------------------------------------------------
// Stage 2: C = A @ Wb^T. m97-structure: 128x128 tile, BK=64, double-buffered
// LDS, global_load_lds w16, XOR-swizzled (row&7) 128B rows. Bijective XCD
// grouping: the 8 bn-blocks sharing an A-panel (same bm) land on one XCD.
// ---------------------------------------------------------------------------
__global__ __launch_bounds__(256)
void proj_kernel(const __hip_bfloat16* __restrict__ A,
                 const __hip_bfloat16* __restrict__ Wb,
                 float* __restrict__ C) {
    __shared__ __align__(16) short As[2][128 * 64];  // 32 KB
    __shared__ __align__(16) short Ws[2][128 * 64];  // 32 KB

    const int t = threadIdx.x;
    const int wave = t >> 6, lane = t & 63;
    const int quad = lane >> 4, lr = lane & 15;
    const int wm = wave >> 1, wn = wave & 1;
    const int bx = blockIdx.x;                 // 0..511
    const int xcd = bx & 7, j = bx >> 3;       // j 0..63
    const int bm = (xcd * 8 + (j >> 3)) * 128;
    const int bn = (j & 7) * 128;

    floatx4 acc[4][4] = {};   // [mb][nb]

    auto stage = [&](int buf, int k0) {
#pragma unroll
        for (int c = 0; c < 4; ++c) {
            const int blk = c * 4 + wave;             // 0..15, wave-uniform
            const int r = blk * 8 + (lane >> 3);
            const int g = (lane & 7) ^ (r & 7);
            const __hip_bfloat16* ga = A + (size_t)(bm + r) * Dv + k0 + g * 8;
            const __hip_bfloat16* gw = Wb + (size_t)(bn + r) * Dv + k0 + g * 8;
            __builtin_amdgcn_global_load_lds(
                (const __attribute__((address_space(1))) unsigned int*)(const void*)ga,
                (__attribute__((address_space(3))) unsigned int*)(void*)&As[buf][blk * 512],
                16, 0, 0);
            __builtin_amdgcn_global_load_lds(
                (const __attribute__((address_space(1))) unsigned int*)(const void*)gw,
                (__attribute__((address_space(3))) unsigned int*)(void*)&Ws[buf][blk * 512],
                16, 0, 0);
        }
    };

    stage(0, 0);

#pragma unroll 2
    for (int it = 0; it < Dv / 64; ++it) {
        const int cur = it & 1;
        __syncthreads();                              // drains vmcnt: buf[cur] staged
        if (it + 1 < Dv / 64) stage(1 - cur, (it + 1) * 64);   // overlaps compute

#pragma unroll
        for (int ks = 0; ks < 2; ++ks) {
            short8 af[4];
#pragma unroll
            for (int mb = 0; mb < 4; ++mb) {
                int row = wm * 64 + mb * 16 + lr;
                af[mb] = *(const short8*)&As[cur][row * 64 + (((ks * 4 + quad) ^ (lr & 7)) << 3)];
            }
#pragma unroll
            for (int nb = 0; nb < 4; ++nb) {
                int row = wn * 64 + nb * 16 + lr;
                short8 bf = *(const short8*)&Ws[cur][row * 64 + (((ks * 4 + quad) ^ (lr & 7)) << 3)];
#pragma unroll
                for (int mb = 0; mb < 4; ++mb)
                    acc[mb][nb] = __builtin_amdgcn_mfma_f32_16x16x32_bf16(af[mb], bf, acc[mb][nb], 0, 0, 0);
            }
        }
    }

    // C/D layout: col = lane&15, row = quad*4 + reg
#pragma unroll
    for (int mb = 0; mb < 4; ++mb)
#pragma unroll
        for (int nb = 0; nb < 4; ++nb) {
            int row = bm + wm * 64 + mb * 16 + quad * 4;
            int col = bn + wn * 64 + nb * 16 + lr;
#pragma unroll
            for (int r = 0; r < 4; ++r)
                C[(size_t)(row + r) * Dv + col] = acc[mb][nb][r];
        }
}

// ---------------------------------------------------------------------------
// Stage 3: LayerNorm in place on d_out (fp32). Biased variance, eps=1e-5.
// ---------------------------------------------------------------------------
__global__ __launch_bounds__(256)
void ln_kernel(float* __restrict__ C,
               const float* __restrict__ g) {
    const int row = blockIdx.x;
    const int t = threadIdx.x;
    const int wave = t >> 6, lane = t & 63;

    float* rp = C + (size_t)row * Dv;
    float4 x = *(const float4*)(rp + t * 4);

    float s = x.x + x.y + x.z + x.w;
    float sq = x.x * x.x + x.y * x.y + x.z * x.z + x.w * x.w;
#pragma unroll
    for (int off = 32; off >= 1; off >>= 1) {
        s += __shfl_xor(s, off);
        sq += __shfl_xor(sq, off);
    }
    __shared__ float ss[4], ssq[4];
    if (lane == 0) { ss[wave] = s; ssq[wave] = sq; }
    __syncthreads();
    s = ss[0] + ss[1] + ss[2] + ss[3];
    sq = ssq[0] + ssq[1] + ssq[2] + ssq[3];

    const float rn = 1.f / (float)Dv;
    float mean = s * rn;
    float var = sq * rn - mean * mean;
    float inv = rsqrtf(var + 1e-5f);

    float4 gv = *(const float4*)(g + t * 4);

    float4 o;
    o.x = (x.x - mean) * inv * gv.x;
    o.y = (x.y - mean) * inv * gv.y;
    o.z = (x.z - mean) * inv * gv.z;
    o.w = (x.w - mean) * inv * gv.w;
    *(float4*)(rp + t * 4) = o;
}

// ---------------------------------------------------------------------------
extern "C" void kernel_launch(void* const* d_in, const int* in_sizes, int n_in,
                              void* d_out, int out_size, void* d_ws, size_t ws_size,
                              hipStream_t stream) {
    const float* q = (const float*)d_in[0];
    const float* k = (const float*)d_in[1];
    const float* v = (const float*)d_in[2];
    const float* W = (const float*)d_in[3];
    const float* g = (const float*)d_in[4];
    float* out = (float*)d_out;

    const size_t attnB = (size_t)Bv * Nv * Dv * 2;       // 16 MiB bf16 attn out
    const size_t wbB = (size_t)Dv * Dv * 2;              // 2 MiB bf16 W
    const size_t kbB = (size_t)Bv * Nv * Dv * 2;         // 16 MiB bf16 K

    __hip_bfloat16* attn = (__hip_bfloat16*)d_ws;
    __hip_bfloat16* Wb = (__hip_bfloat16*)((char*)d_ws + attnB);
    __hip_bfloat16* Kb = (__hip_bfloat16*)((char*)d_ws + attnB + wbB);
    __hip_bfloat16* Vtb = (__hip_bfloat16*)((char*)d_ws + attnB + wbB + kbB);

    prep_all<<<KCONV_BLOCKS + WCONV_BLOCKS + VT_BLOCKS, 256, 0, stream>>>(k, Kb, W, Wb, v, Vtb);
    attn_mfma_pre<<<dim3(32, 16, Bv), 256, 0, stream>>>(q, Kb, Vtb, attn);
    proj_kernel<<<512, 256, 0, stream>>>(attn, Wb, out);
    ln_kernel<<<Bv * Nv, 256, 0, stream>>>(out, g);
}